// Round 3
// baseline (405.600 us; speedup 1.0000x reference)
//
#include <hip/hip_runtime.h>

// B=4, T=2048, D=1024, fp32 in/out, bf16-tolerance threshold.
// prep (cast x + weight transposes + bias concat) -> fused QKV GEMM (V third
// written transposed) -> scores GEMM (bf16 S, causal tile-skip, rev-y) ->
// rowstat (max, 1/sum) -> PV GEMM with inline softmax on A-staging (rev-y) ->
// output proj.
// GEMM core: bf16 MFMA 32x32x16, 128x128 tile, BK=32, global_load_lds w=16,
// XOR chunk swizzle (chunk ^ row&3) applied on the GLOBAL column so the DMA's
// fixed lane->LDS mapping is preserved (permutation within each 64B row).

typedef __attribute__((ext_vector_type(8)))  short short8;     // MFMA A/B frag (8 bf16)
typedef __attribute__((ext_vector_type(16))) float f16a;       // MFMA 32x32 C/D frag
typedef __attribute__((ext_vector_type(4)))  float f4;
typedef __attribute__((ext_vector_type(8)))  unsigned short us8;

#define BM 128
#define BN 128
#define BK 32

__device__ inline unsigned short f2bf(float f) {
    union { float f; unsigned u; } c; c.f = f;
    unsigned u = c.u;
    return (unsigned short)((u + 0x7fffu + ((u >> 16) & 1u)) >> 16);  // RNE
}
__device__ inline float bf2f(unsigned short u) {
    union { unsigned u; float f; } c; c.u = ((unsigned)u) << 16;
    return c.f;
}
__device__ inline void gload16(const void* g, void* l) {
    __builtin_amdgcn_global_load_lds(
        (const __attribute__((address_space(1))) void*)g,
        (__attribute__((address_space(3))) void*)l,
        16, 0, 0);
}

// ---------------------------------------------------------------------------
// C = A[M,K] @ Bt[N,K]^T (+bias), bf16 in, fp32/bf16 out. 32x32x16 core.
// flags: bit0 out-bf16 | bit1 causal tile-skip | bit2 causal K-limit |
//        bit3 reverse-y | bit4 V-split transposed write (n0>=vsplit -> C2)
// ---------------------------------------------------------------------------
__global__ __launch_bounds__(256)
void gemm_bt(const unsigned short* __restrict__ A,
             const unsigned short* __restrict__ Bt,
             void* __restrict__ C,
             const float* __restrict__ bias,
             int M, int N, int K, int lda, int ldb, int ldc,
             long sA, long sB, long sC,
             float scale, int flags,
             unsigned short* __restrict__ C2, long sC2, int Tv, int vsplit)
{
    const int b = blockIdx.z;
    A  += (long)b * sA;
    Bt += (long)b * sB;

    int by = blockIdx.y;
    if (flags & 8) by = gridDim.y - 1 - by;
    const int m0 = by * BM;
    const int n0 = blockIdx.x * BN;

    if ((flags & 2) && n0 > m0 + (BM - 1)) return;

    int kend = K;
    if (flags & 4) { int ke = m0 + BM; kend = ke < K ? ke : K; }
    const int numK = kend / BK;

    __shared__ unsigned short As[BM * BK];   // 8 KB
    __shared__ unsigned short Bs[BN * BK];   // 8 KB

    const int tid  = threadIdx.x;
    const int lane = tid & 63;
    const int wave = tid >> 6;
    const int wm   = wave & 1;
    const int wn   = wave >> 1;
    const int l31  = lane & 31;
    const int kh   = lane >> 5;      // k-half (0/1)

    f16a acc[2][2];
#pragma unroll
    for (int i = 0; i < 2; ++i)
#pragma unroll
        for (int j = 0; j < 2; ++j) acc[i][j] = (f16a)0.0f;

    // staging: chunk e = r*256+tid; row=e>>2; global chunk = (e&3)^(row&3)
    const int erow0 = tid >> 2;
    const int ecol  = (((tid & 3) ^ (erow0 & 3)) << 3);   // swizzled col (elems)

    for (int kt = 0; kt < numK; ++kt) {
        const int k0 = kt * BK;
#pragma unroll
        for (int r = 0; r < 2; ++r) {
            const int row = r * 64 + erow0;
            const unsigned short* ga = A  + (long)(m0 + row) * lda + k0 + ecol;
            const unsigned short* gb = Bt + (long)(n0 + row) * ldb + k0 + ecol;
            const int ldsoff = (r * 256 + wave * 64) * 16;   // bytes, wave-uniform
            gload16(ga, (char*)As + ldsoff);
            gload16(gb, (char*)Bs + ldsoff);
        }
        __syncthreads();

        short8 af[2][2], bv[2][2];   // [kstep][tile]
#pragma unroll
        for (int s = 0; s < 2; ++s) {
            const int csw = (((s * 2 + kh) ^ (l31 & 3)) << 3);
#pragma unroll
            for (int i = 0; i < 2; ++i) {
                af[s][i] = *(const short8*)(As + (wm * 64 + i * 32 + l31) * BK + csw);
                bv[s][i] = *(const short8*)(Bs + (wn * 64 + i * 32 + l31) * BK + csw);
            }
        }
#pragma unroll
        for (int s = 0; s < 2; ++s)
#pragma unroll
            for (int i = 0; i < 2; ++i)
#pragma unroll
                for (int j = 0; j < 2; ++j)
                    acc[i][j] = __builtin_amdgcn_mfma_f32_32x32x16_bf16(
                        af[s][i], bv[s][j], acc[i][j], 0, 0, 0);
        __syncthreads();
    }

    // epilogue: C/D layout col=lane&31, row=(reg&3)+8*(reg>>2)+4*kh (m74/m101)
    const int row_base = m0 + wm * 64 + 4 * kh;
    const int col_base = n0 + wn * 64 + l31;

    float bj[2];
#pragma unroll
    for (int j = 0; j < 2; ++j) bj[j] = bias ? bias[col_base + j * 32] : 0.0f;

    if ((flags & 16) && n0 >= vsplit) {
        // V region: write transposed to C2[b][d][t], packed 4 bf16 (8B) stores
        const int bidx  = m0 >> 11;               // T=2048 rows per batch
        const int tloc0 = (m0 & 2047) + wm * 64 + 4 * kh;
#pragma unroll
        for (int i = 0; i < 2; ++i)
#pragma unroll
            for (int j = 0; j < 2; ++j) {
                const int d = col_base + j * 32 - vsplit;
                unsigned short* base = C2 + (long)bidx * sC2 + (long)d * Tv;
#pragma unroll
                for (int rg = 0; rg < 4; ++rg) {
                    const int tt = tloc0 + i * 32 + 8 * rg;
                    unsigned long long pk = 0;
#pragma unroll
                    for (int rr = 0; rr < 4; ++rr) {
                        float v = acc[i][j][rg * 4 + rr] * scale + bj[j];
                        pk |= (unsigned long long)f2bf(v) << (16 * rr);
                    }
                    *(unsigned long long*)(base + tt) = pk;
                }
            }
        return;
    }

    const bool obf = flags & 1;
    unsigned short* Cb = (unsigned short*)C;
    float*          Cf = (float*)C;
    const long cbase = (long)b * sC;

#pragma unroll
    for (int i = 0; i < 2; ++i) {
        const long roff = cbase + (long)(row_base + i * 32) * ldc;
#pragma unroll
        for (int j = 0; j < 2; ++j) {
            const int col = col_base + j * 32;
#pragma unroll
            for (int reg = 0; reg < 16; ++reg) {
                const int dr = (reg & 3) + 8 * (reg >> 2);
                float v = acc[i][j][reg] * scale + bj[j];
                if (obf) Cb[roff + (long)dr * ldc + col] = f2bf(v);
                else     Cf[roff + (long)dr * ldc + col] = v;
            }
        }
    }
}

// ---------------------------------------------------------------------------
// PV GEMM: O[T,Dm] = softmax-weights @ V^T; A-staging applies exp(s-m)*invl
// with causal mask inline (VGPR path + ds_write, same swizzled LDS layout).
// ---------------------------------------------------------------------------
__global__ __launch_bounds__(256)
void gemm_pv(const unsigned short* __restrict__ S,
             const unsigned short* __restrict__ Vt,
             const float* __restrict__ mrow,
             const float* __restrict__ invl,
             unsigned short* __restrict__ O,
             int T, int Dm)
{
    const int b = blockIdx.z;
    S    += (long)b * T * T;
    Vt   += (long)b * Dm * T;
    O    += (long)b * T * Dm;
    mrow += (long)b * T;
    invl += (long)b * T;

    const int m0 = (gridDim.y - 1 - blockIdx.y) * BM;   // reversed-y
    const int n0 = blockIdx.x * BN;
    const int kend = m0 + BM;        // causal limit
    const int numK = kend / BK;

    __shared__ unsigned short As[BM * BK];
    __shared__ unsigned short Bs[BN * BK];

    const int tid  = threadIdx.x;
    const int lane = tid & 63;
    const int wave = tid >> 6;
    const int wm   = wave & 1;
    const int wn   = wave >> 1;
    const int l31  = lane & 31;
    const int kh   = lane >> 5;

    f16a acc[2][2];
#pragma unroll
    for (int i = 0; i < 2; ++i)
#pragma unroll
        for (int j = 0; j < 2; ++j) acc[i][j] = (f16a)0.0f;

    const int erow0 = tid >> 2;
    const int ecol  = (((tid & 3) ^ (erow0 & 3)) << 3);

    // per-thread row stats (rows fixed across k-iters)
    float mr[2], il[2];
#pragma unroll
    for (int r = 0; r < 2; ++r) {
        const int sr = m0 + r * 64 + erow0;
        mr[r] = mrow[sr];
        il[r] = invl[sr];
    }

    for (int kt = 0; kt < numK; ++kt) {
        const int k0 = kt * BK;
#pragma unroll
        for (int r = 0; r < 2; ++r) {
            const int row = r * 64 + erow0;
            const int sr  = m0 + row;
            // A: load S chunk, apply exp/mask, ds_write (same layout as DMA)
            us8 raw = *(const us8*)(S + (long)sr * T + k0 + ecol);
            us8 p;
#pragma unroll
            for (int jj = 0; jj < 8; ++jj) {
                const int kg = k0 + ecol + jj;
                float e = __expf(bf2f(raw[jj]) - mr[r]) * il[r];
                p[jj] = (kg <= sr) ? f2bf(e) : (unsigned short)0;
            }
            *(us8*)(As + (r * 256 + tid) * 8) = p;
            // B: V^T rows are D-indices, cols are t
            const unsigned short* gb = Vt + (long)(n0 + row) * T + k0 + ecol;
            gload16(gb, (char*)Bs + (r * 256 + wave * 64) * 16);
        }
        __syncthreads();

        short8 af[2][2], bv[2][2];
#pragma unroll
        for (int s = 0; s < 2; ++s) {
            const int csw = (((s * 2 + kh) ^ (l31 & 3)) << 3);
#pragma unroll
            for (int i = 0; i < 2; ++i) {
                af[s][i] = *(const short8*)(As + (wm * 64 + i * 32 + l31) * BK + csw);
                bv[s][i] = *(const short8*)(Bs + (wn * 64 + i * 32 + l31) * BK + csw);
            }
        }
#pragma unroll
        for (int s = 0; s < 2; ++s)
#pragma unroll
            for (int i = 0; i < 2; ++i)
#pragma unroll
                for (int j = 0; j < 2; ++j)
                    acc[i][j] = __builtin_amdgcn_mfma_f32_32x32x16_bf16(
                        af[s][i], bv[s][j], acc[i][j], 0, 0, 0);
        __syncthreads();
    }

    const int row_base = m0 + wm * 64 + 4 * kh;
    const int col_base = n0 + wn * 64 + l31;
#pragma unroll
    for (int i = 0; i < 2; ++i) {
        const long roff = (long)(row_base + i * 32) * Dm;
#pragma unroll
        for (int j = 0; j < 2; ++j) {
            const int col = col_base + j * 32;
#pragma unroll
            for (int reg = 0; reg < 16; ++reg) {
                const int dr = (reg & 3) + 8 * (reg >> 2);
                O[roff + (long)dr * Dm + col] = f2bf(acc[i][j][reg]);
            }
        }
    }
}

// ---------------------------------------------------------------------------
// row stats: m = max(valid), invl = 1/sum(exp(s-m)); one block per row
// ---------------------------------------------------------------------------
__global__ void rowstat(const unsigned short* __restrict__ S,
                        float* __restrict__ mrow, float* __restrict__ invl, int T)
{
    const int t = blockIdx.x;
    const long rowoff = ((long)blockIdx.y * T + t) * T;
    const int L = t + 1;
    const int tid = threadIdx.x;
    const int lane = tid & 63, wave = tid >> 6;
    __shared__ float red[4];

    us8 raw = *(const us8*)(S + rowoff + tid * 8);
    const int i0 = tid * 8;
    float vals[8];
    float m = -INFINITY;
#pragma unroll
    for (int k = 0; k < 8; ++k) {
        float v = (i0 + k < L) ? bf2f(raw[k]) : -INFINITY;
        vals[k] = v;
        m = fmaxf(m, v);
    }
    for (int o = 32; o > 0; o >>= 1) m = fmaxf(m, __shfl_down(m, o));
    if (lane == 0) red[wave] = m;
    __syncthreads();
    m = fmaxf(fmaxf(red[0], red[1]), fmaxf(red[2], red[3]));
    __syncthreads();

    float sum = 0.0f;
#pragma unroll
    for (int k = 0; k < 8; ++k) sum += __expf(vals[k] - m);
    for (int o = 32; o > 0; o >>= 1) sum += __shfl_down(sum, o);
    if (lane == 0) red[wave] = sum;
    __syncthreads();
    if (tid == 0) {
        sum = red[0] + red[1] + red[2] + red[3];
        mrow[(long)blockIdx.y * T + t] = m;
        invl[(long)blockIdx.y * T + t] = 1.0f / sum;
    }
}

// ---------------------------------------------------------------------------
// prep: x cast (blocks [0,8192)) + 4 weight transposes [8192,12288) +
//       bias concat [12288,12292)
// ---------------------------------------------------------------------------
__global__ void prep(const float* __restrict__ x,
                     const float* __restrict__ Wq, const float* __restrict__ Wk,
                     const float* __restrict__ Wv, const float* __restrict__ Wh,
                     const float* __restrict__ bq, const float* __restrict__ bk,
                     const float* __restrict__ bv,
                     unsigned short* __restrict__ Xbf,
                     unsigned short* __restrict__ Wqkvt,
                     unsigned short* __restrict__ Wht,
                     float* __restrict__ bqkv)
{
    __shared__ unsigned short tsh[32][33];
    const int bid = blockIdx.x;
    const int tid = threadIdx.x;

    if (bid < 8192) {                      // cast x: 4 f32 -> 4 bf16 per thread
        const int i = bid * 256 + tid;
        f4 v = ((const f4*)x)[i];
        unsigned long long p = (unsigned long long)f2bf(v.x)
                             | ((unsigned long long)f2bf(v.y) << 16)
                             | ((unsigned long long)f2bf(v.z) << 32)
                             | ((unsigned long long)f2bf(v.w) << 48);
        ((unsigned long long*)Xbf)[i] = p;
    } else if (bid < 12288) {              // transpose+cast weights
        const int wi = bid - 8192;
        const int w = wi >> 10, tile = wi & 1023;
        const float* src = (w == 0) ? Wq : (w == 1) ? Wk : (w == 2) ? Wv : Wh;
        unsigned short* dst = (w < 3) ? (Wqkvt + (size_t)w * 1024 * 1024) : Wht;
        const int c0 = (tile & 31) * 32, r0 = (tile >> 5) * 32;
        const int xx = tid & 31, yy = tid >> 5;
        for (int i = yy; i < 32; i += 8)
            tsh[i][xx] = f2bf(src[(long)(r0 + i) * 1024 + c0 + xx]);
        __syncthreads();
        for (int i = yy; i < 32; i += 8)
            dst[(long)(c0 + i) * 1024 + r0 + xx] = tsh[xx][i];
    } else {                               // bias concat
        const int i = (bid - 12288) * 256 + tid;
        if (i < 1024) { bqkv[i] = bq[i]; bqkv[1024 + i] = bk[i]; bqkv[2048 + i] = bv[i]; }
    }
}

// ---------------------------------------------------------------------------
extern "C" void kernel_launch(void* const* d_in, const int* in_sizes, int n_in,
                              void* d_out, int out_size, void* d_ws, size_t ws_size,
                              hipStream_t stream)
{
    const float* x  = (const float*)d_in[0];
    const float* Wq = (const float*)d_in[1];
    const float* bq = (const float*)d_in[2];
    const float* Wk = (const float*)d_in[3];
    const float* bk = (const float*)d_in[4];
    const float* Wv = (const float*)d_in[5];
    const float* bv = (const float*)d_in[6];
    const float* Wh = (const float*)d_in[7];
    const float* bh = (const float*)d_in[8];
    float* out = (float*)d_out;

    const int  Bb = 4, T = 2048, Dm = 1024;
    const long BT = (long)Bb * T;

    unsigned short* ws = (unsigned short*)d_ws;
    size_t o = 0;
    unsigned short* Xbf   = ws + o; o += (size_t)BT * Dm;         // 16 MB
    unsigned short* Wqkvt = ws + o; o += (size_t)3 * Dm * Dm;     //  6 MB
    unsigned short* Wht   = ws + o; o += (size_t)Dm * Dm;         //  2 MB
    float* bqkv = (float*)(ws + o); o += (size_t)3 * Dm * 2;      // 12 KB
    unsigned short* QKV   = ws + o; o += (size_t)BT * 3 * Dm;     // 48 MB (V third unused)
    unsigned short* Vt    = ws + o; o += (size_t)BT * Dm;         // 16 MB
    unsigned short* S     = ws + o; o += (size_t)Bb * T * T;      // 32 MB
    float* mrowb = (float*)(ws + o); o += (size_t)BT * 2;         // 32 KB
    float* invlb = (float*)(ws + o); o += (size_t)BT * 2;         // 32 KB
    unsigned short* Ob    = ws + o;                               // 16 MB

    const dim3 blk(256);
    const long sRow3 = (long)T * 3 * Dm;

    // 1. prep: cast x + weight transposes + bias concat
    prep<<<12292, blk, 0, stream>>>(x, Wq, Wk, Wv, Wh, bq, bk, bv,
                                    Xbf, Wqkvt, Wht, bqkv);

    // 2. fused QKV projection; V third written transposed into Vt
    gemm_bt<<<dim3(3 * Dm / BN, BT / BM, 1), blk, 0, stream>>>(
        Xbf, Wqkvt, QKV, bqkv, (int)BT, 3 * Dm, Dm, Dm, Dm, 3 * Dm,
        0, 0, 0, 1.0f, 1 | 16, Vt, (long)Dm * T, T, 2 * Dm);

    // 3. scores = Q @ K^T * 1/sqrt(D) -> bf16 S, causal tile-skip, rev-y
    gemm_bt<<<dim3(T / BN, T / BM, Bb), blk, 0, stream>>>(
        QKV, QKV + Dm, S, nullptr, T, T, Dm, 3 * Dm, 3 * Dm, T,
        sRow3, sRow3, (long)T * T, 1.0f / 32.0f, 1 | 2 | 8,
        nullptr, 0, 0, 0);

    // 4. row stats (max, 1/sum)
    rowstat<<<dim3(T, Bb), blk, 0, stream>>>(S, mrowb, invlb, T);

    // 5. O = softmax(S) @ V^T, softmax fused into A-staging, causal, rev-y
    gemm_pv<<<dim3(Dm / BN, T / BM, Bb), blk, 0, stream>>>(
        S, Vt, mrowb, invlb, Ob, T, Dm);

    // 6. out = O @ Wh^T + bh -> fp32
    gemm_bt<<<dim3(Dm / BN, BT / BM, 1), blk, 0, stream>>>(
        Ob, Wht, out, bh, (int)BT, Dm, Dm, Dm, Dm, Dm,
        0, 0, 0, 1.0f, 0, nullptr, 0, 0, 0);
}

// Round 4
// 374.435 us; speedup vs baseline: 1.0832x; 1.0832x over previous
//
#include <hip/hip_runtime.h>

// B=4, T=2048, D=1024, fp32 in/out, bf16-tolerance threshold.
// prep -> fused QKV GEMM (V third written transposed) ->
// scores GEMM emitting P' = exp(s)*causal_mask (bf16, no max-sub needed:
// |s| <~ 2) -> rowsum (invl = 1/sum) -> PV GEMM (plain async-DMA, row-scaled
// epilogue) -> output proj.
// GEMM core: bf16 MFMA 32x32x16, 128x128 tile, BK=32, global_load_lds w=16,
// XOR chunk swizzle applied on the GLOBAL column (DMA lane->LDS map preserved).

typedef __attribute__((ext_vector_type(8)))  short short8;     // MFMA A/B frag
typedef __attribute__((ext_vector_type(16))) float f16a;       // MFMA 32x32 C/D
typedef __attribute__((ext_vector_type(4)))  float f4;
typedef __attribute__((ext_vector_type(8)))  unsigned short us8;

#define BM 128
#define BN 128
#define BK 32

__device__ inline unsigned short f2bf(float f) {
    union { float f; unsigned u; } c; c.f = f;
    unsigned u = c.u;
    return (unsigned short)((u + 0x7fffu + ((u >> 16) & 1u)) >> 16);  // RNE
}
__device__ inline float bf2f(unsigned short u) {
    union { unsigned u; float f; } c; c.u = ((unsigned)u) << 16;
    return c.f;
}
__device__ inline void gload16(const void* g, void* l) {
    __builtin_amdgcn_global_load_lds(
        (const __attribute__((address_space(1))) void*)g,
        (__attribute__((address_space(3))) void*)l,
        16, 0, 0);
}

// ---------------------------------------------------------------------------
// C = A[M,K] @ Bt[N,K]^T (+bias), bf16 in, fp32/bf16 out. 32x32x16 core.
// flags: bit0 out-bf16 | bit1 causal tile-skip | bit2 causal K-limit |
//        bit3 reverse-y | bit4 V-split transposed write (n0>=vsplit -> C2) |
//        bit5 row-scale epilogue (v *= rowscale[b*M+row]) |
//        bit6 exp + causal-mask epilogue (P' = exp(v) if col<=row else 0)
// ---------------------------------------------------------------------------
__global__ __launch_bounds__(256)
void gemm_bt(const unsigned short* __restrict__ A,
             const unsigned short* __restrict__ Bt,
             void* __restrict__ C,
             const float* __restrict__ bias,
             int M, int N, int K, int lda, int ldb, int ldc,
             long sA, long sB, long sC,
             float scale, int flags,
             unsigned short* __restrict__ C2, long sC2, int Tv, int vsplit,
             const float* __restrict__ rowscale)
{
    const int b = blockIdx.z;
    A  += (long)b * sA;
    Bt += (long)b * sB;
    if (flags & 32) rowscale += (long)b * M;

    int by = blockIdx.y;
    if (flags & 8) by = gridDim.y - 1 - by;
    const int m0 = by * BM;
    const int n0 = blockIdx.x * BN;

    if ((flags & 2) && n0 > m0 + (BM - 1)) return;

    int kend = K;
    if (flags & 4) { int ke = m0 + BM; kend = ke < K ? ke : K; }
    const int numK = kend / BK;

    __shared__ unsigned short As[BM * BK];   // 8 KB
    __shared__ unsigned short Bs[BN * BK];   // 8 KB

    const int tid  = threadIdx.x;
    const int lane = tid & 63;
    const int wave = tid >> 6;
    const int wm   = wave & 1;
    const int wn   = wave >> 1;
    const int l31  = lane & 31;
    const int kh   = lane >> 5;      // k-half

    f16a acc[2][2];
#pragma unroll
    for (int i = 0; i < 2; ++i)
#pragma unroll
        for (int j = 0; j < 2; ++j) acc[i][j] = (f16a)0.0f;

    // staging: chunk e = r*256+tid; row=e>>2; global chunk = (e&3)^(row&3)
    const int erow0 = tid >> 2;
    const int ecol  = (((tid & 3) ^ (erow0 & 3)) << 3);

    for (int kt = 0; kt < numK; ++kt) {
        const int k0 = kt * BK;
#pragma unroll
        for (int r = 0; r < 2; ++r) {
            const int row = r * 64 + erow0;
            const unsigned short* ga = A  + (long)(m0 + row) * lda + k0 + ecol;
            const unsigned short* gb = Bt + (long)(n0 + row) * ldb + k0 + ecol;
            const int ldsoff = (r * 256 + wave * 64) * 16;   // bytes, wave-uniform
            gload16(ga, (char*)As + ldsoff);
            gload16(gb, (char*)Bs + ldsoff);
        }
        __syncthreads();

        short8 af[2][2], bv[2][2];   // [kstep][tile]
#pragma unroll
        for (int s = 0; s < 2; ++s) {
            const int csw = (((s * 2 + kh) ^ (l31 & 3)) << 3);
#pragma unroll
            for (int i = 0; i < 2; ++i) {
                af[s][i] = *(const short8*)(As + (wm * 64 + i * 32 + l31) * BK + csw);
                bv[s][i] = *(const short8*)(Bs + (wn * 64 + i * 32 + l31) * BK + csw);
            }
        }
#pragma unroll
        for (int s = 0; s < 2; ++s)
#pragma unroll
            for (int i = 0; i < 2; ++i)
#pragma unroll
                for (int j = 0; j < 2; ++j)
                    acc[i][j] = __builtin_amdgcn_mfma_f32_32x32x16_bf16(
                        af[s][i], bv[s][j], acc[i][j], 0, 0, 0);
        __syncthreads();
    }

    // epilogue: C/D layout col=lane&31, row=(reg&3)+8*(reg>>2)+4*kh (m74/m101)
    const int row_base = m0 + wm * 64 + 4 * kh;
    const int col_base = n0 + wn * 64 + l31;

    float bj[2];
#pragma unroll
    for (int j = 0; j < 2; ++j) bj[j] = bias ? bias[col_base + j * 32] : 0.0f;

    if ((flags & 16) && n0 >= vsplit) {
        // V region: write transposed to C2[b][d][t], packed 4 bf16 (8B) stores
        const int bidx  = m0 >> 11;               // T=2048 rows per batch
        const int tloc0 = (m0 & 2047) + wm * 64 + 4 * kh;
#pragma unroll
        for (int i = 0; i < 2; ++i)
#pragma unroll
            for (int j = 0; j < 2; ++j) {
                const int d = col_base + j * 32 - vsplit;
                unsigned short* base = C2 + (long)bidx * sC2 + (long)d * Tv;
#pragma unroll
                for (int rg = 0; rg < 4; ++rg) {
                    const int tt = tloc0 + i * 32 + 8 * rg;
                    unsigned long long pk = 0;
#pragma unroll
                    for (int rr = 0; rr < 4; ++rr) {
                        float v = acc[i][j][rg * 4 + rr] * scale + bj[j];
                        pk |= (unsigned long long)f2bf(v) << (16 * rr);
                    }
                    *(unsigned long long*)(base + tt) = pk;
                }
            }
        return;
    }

    const bool obf = flags & 1;
    unsigned short* Cb = (unsigned short*)C;
    float*          Cf = (float*)C;
    const long cbase = (long)b * sC;

#pragma unroll
    for (int i = 0; i < 2; ++i) {
#pragma unroll
        for (int j = 0; j < 2; ++j) {
            const int col = col_base + j * 32;
#pragma unroll
            for (int reg = 0; reg < 16; ++reg) {
                const int dr  = (reg & 3) + 8 * (reg >> 2);
                const int row = row_base + i * 32 + dr;
                float v = acc[i][j][reg] * scale + bj[j];
                if (flags & 64) { v = __expf(v); if (col > row) v = 0.0f; }
                if (flags & 32) v *= rowscale[row];
                const long off = cbase + (long)row * ldc + col;
                if (obf) Cb[off] = f2bf(v);
                else     Cf[off] = v;
            }
        }
    }
}

// ---------------------------------------------------------------------------
// rowsum: invl[row] = 1 / sum(P'[row, 0..t]) ; one 256-thread block per row
// ---------------------------------------------------------------------------
__global__ void rowsum(const unsigned short* __restrict__ P,
                       float* __restrict__ invl, int T)
{
    const int t = blockIdx.x;
    const long rowoff = ((long)blockIdx.y * T + t) * T;
    const int L = t + 1;
    const int tid = threadIdx.x;
    const int lane = tid & 63, wave = tid >> 6;
    __shared__ float red[4];

    us8 raw = *(const us8*)(P + rowoff + tid * 8);
    const int i0 = tid * 8;
    float sum = 0.0f;
#pragma unroll
    for (int k = 0; k < 8; ++k)
        if (i0 + k < L) sum += bf2f(raw[k]);
    for (int o = 32; o > 0; o >>= 1) sum += __shfl_down(sum, o);
    if (lane == 0) red[wave] = sum;
    __syncthreads();
    if (tid == 0) {
        sum = red[0] + red[1] + red[2] + red[3];
        invl[(long)blockIdx.y * T + t] = 1.0f / sum;
    }
}

// ---------------------------------------------------------------------------
// prep: x cast [0,8192) + weight transposes [8192,12288) + bias concat
// ---------------------------------------------------------------------------
__global__ void prep(const float* __restrict__ x,
                     const float* __restrict__ Wq, const float* __restrict__ Wk,
                     const float* __restrict__ Wv, const float* __restrict__ Wh,
                     const float* __restrict__ bq, const float* __restrict__ bk,
                     const float* __restrict__ bv,
                     unsigned short* __restrict__ Xbf,
                     unsigned short* __restrict__ Wqkvt,
                     unsigned short* __restrict__ Wht,
                     float* __restrict__ bqkv)
{
    __shared__ unsigned short tsh[32][33];
    const int bid = blockIdx.x;
    const int tid = threadIdx.x;

    if (bid < 8192) {
        const int i = bid * 256 + tid;
        f4 v = ((const f4*)x)[i];
        unsigned long long p = (unsigned long long)f2bf(v.x)
                             | ((unsigned long long)f2bf(v.y) << 16)
                             | ((unsigned long long)f2bf(v.z) << 32)
                             | ((unsigned long long)f2bf(v.w) << 48);
        ((unsigned long long*)Xbf)[i] = p;
    } else if (bid < 12288) {
        const int wi = bid - 8192;
        const int w = wi >> 10, tile = wi & 1023;
        const float* src = (w == 0) ? Wq : (w == 1) ? Wk : (w == 2) ? Wv : Wh;
        unsigned short* dst = (w < 3) ? (Wqkvt + (size_t)w * 1024 * 1024) : Wht;
        const int c0 = (tile & 31) * 32, r0 = (tile >> 5) * 32;
        const int xx = tid & 31, yy = tid >> 5;
        for (int i = yy; i < 32; i += 8)
            tsh[i][xx] = f2bf(src[(long)(r0 + i) * 1024 + c0 + xx]);
        __syncthreads();
        for (int i = yy; i < 32; i += 8)
            dst[(long)(c0 + i) * 1024 + r0 + xx] = tsh[xx][i];
    } else {
        const int i = (bid - 12288) * 256 + tid;
        if (i < 1024) { bqkv[i] = bq[i]; bqkv[1024 + i] = bk[i]; bqkv[2048 + i] = bv[i]; }
    }
}

// ---------------------------------------------------------------------------
extern "C" void kernel_launch(void* const* d_in, const int* in_sizes, int n_in,
                              void* d_out, int out_size, void* d_ws, size_t ws_size,
                              hipStream_t stream)
{
    const float* x  = (const float*)d_in[0];
    const float* Wq = (const float*)d_in[1];
    const float* bq = (const float*)d_in[2];
    const float* Wk = (const float*)d_in[3];
    const float* bk = (const float*)d_in[4];
    const float* Wv = (const float*)d_in[5];
    const float* bv = (const float*)d_in[6];
    const float* Wh = (const float*)d_in[7];
    const float* bh = (const float*)d_in[8];
    float* out = (float*)d_out;

    const int  Bb = 4, T = 2048, Dm = 1024;
    const long BT = (long)Bb * T;

    unsigned short* ws = (unsigned short*)d_ws;
    size_t o = 0;
    unsigned short* Xbf   = ws + o; o += (size_t)BT * Dm;         // 16 MB
    unsigned short* Wqkvt = ws + o; o += (size_t)3 * Dm * Dm;     //  6 MB
    unsigned short* Wht   = ws + o; o += (size_t)Dm * Dm;         //  2 MB
    float* bqkv = (float*)(ws + o); o += (size_t)3 * Dm * 2;      // 12 KB
    unsigned short* QKV   = ws + o; o += (size_t)BT * 3 * Dm;     // 48 MB
    unsigned short* Vt    = ws + o; o += (size_t)BT * Dm;         // 16 MB
    unsigned short* Pp    = ws + o; o += (size_t)Bb * T * T;      // 32 MB (P' = exp(s))
    float* invlb = (float*)(ws + o); o += (size_t)BT * 2;         // 32 KB
    unsigned short* Ob    = ws + o;                               // 16 MB

    const dim3 blk(256);
    const long sRow3 = (long)T * 3 * Dm;

    // 1. prep
    prep<<<12292, blk, 0, stream>>>(x, Wq, Wk, Wv, Wh, bq, bk, bv,
                                    Xbf, Wqkvt, Wht, bqkv);

    // 2. fused QKV projection; V third written transposed into Vt
    gemm_bt<<<dim3(3 * Dm / BN, BT / BM, 1), blk, 0, stream>>>(
        Xbf, Wqkvt, QKV, bqkv, (int)BT, 3 * Dm, Dm, Dm, Dm, 3 * Dm,
        0, 0, 0, 1.0f, 1 | 16, Vt, (long)Dm * T, T, 2 * Dm, nullptr);

    // 3. P' = exp(Q@K^T / 32) * causal_mask -> bf16, tile-skip, rev-y
    gemm_bt<<<dim3(T / BN, T / BM, Bb), blk, 0, stream>>>(
        QKV, QKV + Dm, Pp, nullptr, T, T, Dm, 3 * Dm, 3 * Dm, T,
        sRow3, sRow3, (long)T * T, 1.0f / 32.0f, 1 | 2 | 8 | 64,
        nullptr, 0, 0, 0, nullptr);

    // 4. invl = 1/rowsum(P')
    rowsum<<<dim3(T, Bb), blk, 0, stream>>>(Pp, invlb, T);

    // 5. O = (P' @ V^T) * invl[row], plain DMA GEMM, causal K-limit, rev-y
    gemm_bt<<<dim3(Dm / BN, T / BM, Bb), blk, 0, stream>>>(
        Pp, Vt, Ob, nullptr, T, Dm, T, T, T, Dm,
        (long)T * T, (long)Dm * T, (long)T * Dm, 1.0f, 1 | 4 | 8 | 32,
        nullptr, 0, 0, 0, invlb);

    // 6. out = O @ Wh^T + bh -> fp32
    gemm_bt<<<dim3(Dm / BN, BT / BM, 1), blk, 0, stream>>>(
        Ob, Wht, out, bh, (int)BT, Dm, Dm, Dm, Dm, Dm,
        0, 0, 0, 1.0f, 0, nullptr, 0, 0, 0, nullptr);
}

// Round 5
// 352.419 us; speedup vs baseline: 1.1509x; 1.0625x over previous
//
#include <hip/hip_runtime.h>

// B=4, T=2048, D=1024, fp32 in/out, bf16-tolerance threshold.
// prep -> fused QKV GEMM (V third written transposed) ->
// scores GEMM emitting P' = exp(s)*causal_mask (bf16, no max-sub needed:
// |s| <~ 2) -> rowsum (invl = 1/sum) -> PV GEMM (row-scaled epilogue) ->
// output proj.
// GEMM core: bf16 MFMA 32x32x16, 128x128 tile, BK=32, global_load_lds w=16.
// LDS swizzle: chunk ^= (row>>1)&3 applied on the GLOBAL column (DMA
// lane->LDS map preserved; permutation stays inside each 64B row).
// Rationale: bank group of a 16B chunk = (row*16+chunk*4)%32; rows alias
// every 2 rows, so mixing by (row>>1)&3 spreads each parity class uniformly
// over the 4 chunk groups -> uniform bank load for wave64 ds_read_b128.
// (R4's l31&3 swizzle put 8 same-parity lanes on one group: 18.9M conflicts.)

typedef __attribute__((ext_vector_type(8)))  short short8;     // MFMA A/B frag
typedef __attribute__((ext_vector_type(16))) float f16a;       // MFMA 32x32 C/D
typedef __attribute__((ext_vector_type(4)))  float f4;
typedef __attribute__((ext_vector_type(8)))  unsigned short us8;

#define BM 128
#define BN 128
#define BK 32

__device__ inline unsigned short f2bf(float f) {
    union { float f; unsigned u; } c; c.f = f;
    unsigned u = c.u;
    return (unsigned short)((u + 0x7fffu + ((u >> 16) & 1u)) >> 16);  // RNE
}
__device__ inline float bf2f(unsigned short u) {
    union { unsigned u; float f; } c; c.u = ((unsigned)u) << 16;
    return c.f;
}
__device__ inline void gload16(const void* g, void* l) {
    __builtin_amdgcn_global_load_lds(
        (const __attribute__((address_space(1))) void*)g,
        (__attribute__((address_space(3))) void*)l,
        16, 0, 0);
}

// ---------------------------------------------------------------------------
// C = A[M,K] @ Bt[N,K]^T (+bias), bf16 in, fp32/bf16 out. 32x32x16 core.
// flags: bit0 out-bf16 | bit1 causal tile-skip | bit2 causal K-limit |
//        bit3 reverse-y | bit4 V-split transposed write (n0>=vsplit -> C2) |
//        bit5 row-scale epilogue | bit6 exp + causal-mask epilogue
// ---------------------------------------------------------------------------
__global__ __launch_bounds__(256)
void gemm_bt(const unsigned short* __restrict__ A,
             const unsigned short* __restrict__ Bt,
             void* __restrict__ C,
             const float* __restrict__ bias,
             int M, int N, int K, int lda, int ldb, int ldc,
             long sA, long sB, long sC,
             float scale, int flags,
             unsigned short* __restrict__ C2, long sC2, int Tv, int vsplit,
             const float* __restrict__ rowscale)
{
    const int b = blockIdx.z;
    A  += (long)b * sA;
    Bt += (long)b * sB;
    if (flags & 32) rowscale += (long)b * M;

    int by = blockIdx.y;
    if (flags & 8) by = gridDim.y - 1 - by;
    const int m0 = by * BM;
    const int n0 = blockIdx.x * BN;

    if ((flags & 2) && n0 > m0 + (BM - 1)) return;

    int kend = K;
    if (flags & 4) { int ke = m0 + BM; kend = ke < K ? ke : K; }
    const int numK = kend / BK;

    __shared__ unsigned short As[BM * BK];   // 8 KB
    __shared__ unsigned short Bs[BN * BK];   // 8 KB

    const int tid  = threadIdx.x;
    const int lane = tid & 63;
    const int wave = tid >> 6;
    const int wm   = wave & 1;
    const int wn   = wave >> 1;
    const int l31  = lane & 31;
    const int kh   = lane >> 5;      // k-half

    f16a acc[2][2];
#pragma unroll
    for (int i = 0; i < 2; ++i)
#pragma unroll
        for (int j = 0; j < 2; ++j) acc[i][j] = (f16a)0.0f;

    // staging: chunk e = r*256+tid; row=e>>2; global chunk = (e&3)^((row>>1)&3)
    const int erow0 = tid >> 2;
    const int ecol  = (((tid & 3) ^ ((erow0 >> 1) & 3)) << 3);

    for (int kt = 0; kt < numK; ++kt) {
        const int k0 = kt * BK;
#pragma unroll
        for (int r = 0; r < 2; ++r) {
            const int row = r * 64 + erow0;
            const unsigned short* ga = A  + (long)(m0 + row) * lda + k0 + ecol;
            const unsigned short* gb = Bt + (long)(n0 + row) * ldb + k0 + ecol;
            const int ldsoff = (r * 256 + wave * 64) * 16;   // bytes, wave-uniform
            gload16(ga, (char*)As + ldsoff);
            gload16(gb, (char*)Bs + ldsoff);
        }
        __syncthreads();

        short8 af[2][2], bv[2][2];   // [kstep][tile]
#pragma unroll
        for (int s = 0; s < 2; ++s) {
            const int csw = (((s * 2 + kh) ^ ((l31 >> 1) & 3)) << 3);
#pragma unroll
            for (int i = 0; i < 2; ++i) {
                af[s][i] = *(const short8*)(As + (wm * 64 + i * 32 + l31) * BK + csw);
                bv[s][i] = *(const short8*)(Bs + (wn * 64 + i * 32 + l31) * BK + csw);
            }
        }
#pragma unroll
        for (int s = 0; s < 2; ++s)
#pragma unroll
            for (int i = 0; i < 2; ++i)
#pragma unroll
                for (int j = 0; j < 2; ++j)
                    acc[i][j] = __builtin_amdgcn_mfma_f32_32x32x16_bf16(
                        af[s][i], bv[s][j], acc[i][j], 0, 0, 0);
        __syncthreads();
    }

    // epilogue: C/D layout col=lane&31, row=(reg&3)+8*(reg>>2)+4*kh (m74/m101)
    const int row_base = m0 + wm * 64 + 4 * kh;
    const int col_base = n0 + wn * 64 + l31;

    float bj[2];
#pragma unroll
    for (int j = 0; j < 2; ++j) bj[j] = bias ? bias[col_base + j * 32] : 0.0f;

    if ((flags & 16) && n0 >= vsplit) {
        // V region: write transposed to C2[b][d][t], packed 4 bf16 (8B) stores
        const int bidx  = m0 >> 11;               // T=2048 rows per batch
        const int tloc0 = (m0 & 2047) + wm * 64 + 4 * kh;
#pragma unroll
        for (int i = 0; i < 2; ++i)
#pragma unroll
            for (int j = 0; j < 2; ++j) {
                const int d = col_base + j * 32 - vsplit;
                unsigned short* base = C2 + (long)bidx * sC2 + (long)d * Tv;
#pragma unroll
                for (int rg = 0; rg < 4; ++rg) {
                    const int tt = tloc0 + i * 32 + 8 * rg;
                    unsigned long long pk = 0;
#pragma unroll
                    for (int rr = 0; rr < 4; ++rr) {
                        float v = acc[i][j][rg * 4 + rr] * scale + bj[j];
                        pk |= (unsigned long long)f2bf(v) << (16 * rr);
                    }
                    *(unsigned long long*)(base + tt) = pk;
                }
            }
        return;
    }

    const bool obf = flags & 1;
    unsigned short* Cb = (unsigned short*)C;
    float*          Cf = (float*)C;
    const long cbase = (long)b * sC;

#pragma unroll
    for (int i = 0; i < 2; ++i) {
#pragma unroll
        for (int j = 0; j < 2; ++j) {
            const int col = col_base + j * 32;
#pragma unroll
            for (int reg = 0; reg < 16; ++reg) {
                const int dr  = (reg & 3) + 8 * (reg >> 2);
                const int row = row_base + i * 32 + dr;
                float v = acc[i][j][reg] * scale + bj[j];
                if (flags & 64) { v = __expf(v); if (col > row) v = 0.0f; }
                if (flags & 32) v *= rowscale[row];
                const long off = cbase + (long)row * ldc + col;
                if (obf) Cb[off] = f2bf(v);
                else     Cf[off] = v;
            }
        }
    }
}

// ---------------------------------------------------------------------------
// rowsum: invl[row] = 1 / sum(P'[row, 0..t]) ; one 256-thread block per row
// ---------------------------------------------------------------------------
__global__ void rowsum(const unsigned short* __restrict__ P,
                       float* __restrict__ invl, int T)
{
    const int t = blockIdx.x;
    const long rowoff = ((long)blockIdx.y * T + t) * T;
    const int L = t + 1;
    const int tid = threadIdx.x;
    const int lane = tid & 63, wave = tid >> 6;
    __shared__ float red[4];

    us8 raw = *(const us8*)(P + rowoff + tid * 8);
    const int i0 = tid * 8;
    float sum = 0.0f;
#pragma unroll
    for (int k = 0; k < 8; ++k)
        if (i0 + k < L) sum += bf2f(raw[k]);
    for (int o = 32; o > 0; o >>= 1) sum += __shfl_down(sum, o);
    if (lane == 0) red[wave] = sum;
    __syncthreads();
    if (tid == 0) {
        sum = red[0] + red[1] + red[2] + red[3];
        invl[(long)blockIdx.y * T + t] = 1.0f / sum;
    }
}

// ---------------------------------------------------------------------------
// prep: x cast [0,8192) + weight transposes [8192,12288) + bias concat
// ---------------------------------------------------------------------------
__global__ void prep(const float* __restrict__ x,
                     const float* __restrict__ Wq, const float* __restrict__ Wk,
                     const float* __restrict__ Wv, const float* __restrict__ Wh,
                     const float* __restrict__ bq, const float* __restrict__ bk,
                     const float* __restrict__ bv,
                     unsigned short* __restrict__ Xbf,
                     unsigned short* __restrict__ Wqkvt,
                     unsigned short* __restrict__ Wht,
                     float* __restrict__ bqkv)
{
    __shared__ unsigned short tsh[32][33];
    const int bid = blockIdx.x;
    const int tid = threadIdx.x;

    if (bid < 8192) {
        const int i = bid * 256 + tid;
        f4 v = ((const f4*)x)[i];
        unsigned long long p = (unsigned long long)f2bf(v.x)
                             | ((unsigned long long)f2bf(v.y) << 16)
                             | ((unsigned long long)f2bf(v.z) << 32)
                             | ((unsigned long long)f2bf(v.w) << 48);
        ((unsigned long long*)Xbf)[i] = p;
    } else if (bid < 12288) {
        const int wi = bid - 8192;
        const int w = wi >> 10, tile = wi & 1023;
        const float* src = (w == 0) ? Wq : (w == 1) ? Wk : (w == 2) ? Wv : Wh;
        unsigned short* dst = (w < 3) ? (Wqkvt + (size_t)w * 1024 * 1024) : Wht;
        const int c0 = (tile & 31) * 32, r0 = (tile >> 5) * 32;
        const int xx = tid & 31, yy = tid >> 5;
        for (int i = yy; i < 32; i += 8)
            tsh[i][xx] = f2bf(src[(long)(r0 + i) * 1024 + c0 + xx]);
        __syncthreads();
        for (int i = yy; i < 32; i += 8)
            dst[(long)(c0 + i) * 1024 + r0 + xx] = tsh[xx][i];
    } else {
        const int i = (bid - 12288) * 256 + tid;
        if (i < 1024) { bqkv[i] = bq[i]; bqkv[1024 + i] = bk[i]; bqkv[2048 + i] = bv[i]; }
    }
}

// ---------------------------------------------------------------------------
extern "C" void kernel_launch(void* const* d_in, const int* in_sizes, int n_in,
                              void* d_out, int out_size, void* d_ws, size_t ws_size,
                              hipStream_t stream)
{
    const float* x  = (const float*)d_in[0];
    const float* Wq = (const float*)d_in[1];
    const float* bq = (const float*)d_in[2];
    const float* Wk = (const float*)d_in[3];
    const float* bk = (const float*)d_in[4];
    const float* Wv = (const float*)d_in[5];
    const float* bv = (const float*)d_in[6];
    const float* Wh = (const float*)d_in[7];
    const float* bh = (const float*)d_in[8];
    float* out = (float*)d_out;

    const int  Bb = 4, T = 2048, Dm = 1024;
    const long BT = (long)Bb * T;

    unsigned short* ws = (unsigned short*)d_ws;
    size_t o = 0;
    unsigned short* Xbf   = ws + o; o += (size_t)BT * Dm;         // 16 MB
    unsigned short* Wqkvt = ws + o; o += (size_t)3 * Dm * Dm;     //  6 MB
    unsigned short* Wht   = ws + o; o += (size_t)Dm * Dm;         //  2 MB
    float* bqkv = (float*)(ws + o); o += (size_t)3 * Dm * 2;      // 12 KB
    unsigned short* QKV   = ws + o; o += (size_t)BT * 3 * Dm;     // 48 MB
    unsigned short* Vt    = ws + o; o += (size_t)BT * Dm;         // 16 MB
    unsigned short* Pp    = ws + o; o += (size_t)Bb * T * T;      // 32 MB (P' = exp(s))
    float* invlb = (float*)(ws + o); o += (size_t)BT * 2;         // 32 KB
    unsigned short* Ob    = ws + o;                               // 16 MB

    const dim3 blk(256);
    const long sRow3 = (long)T * 3 * Dm;

    // 1. prep
    prep<<<12292, blk, 0, stream>>>(x, Wq, Wk, Wv, Wh, bq, bk, bv,
                                    Xbf, Wqkvt, Wht, bqkv);

    // 2. fused QKV projection; V third written transposed into Vt
    gemm_bt<<<dim3(3 * Dm / BN, BT / BM, 1), blk, 0, stream>>>(
        Xbf, Wqkvt, QKV, bqkv, (int)BT, 3 * Dm, Dm, Dm, Dm, 3 * Dm,
        0, 0, 0, 1.0f, 1 | 16, Vt, (long)Dm * T, T, 2 * Dm, nullptr);

    // 3. P' = exp(Q@K^T / 32) * causal_mask -> bf16, tile-skip, rev-y
    gemm_bt<<<dim3(T / BN, T / BM, Bb), blk, 0, stream>>>(
        QKV, QKV + Dm, Pp, nullptr, T, T, Dm, 3 * Dm, 3 * Dm, T,
        sRow3, sRow3, (long)T * T, 1.0f / 32.0f, 1 | 2 | 8 | 64,
        nullptr, 0, 0, 0, nullptr);

    // 4. invl = 1/rowsum(P')
    rowsum<<<dim3(T, Bb), blk, 0, stream>>>(Pp, invlb, T);

    // 5. O = (P' @ V^T) * invl[row], plain DMA GEMM, causal K-limit, rev-y
    gemm_bt<<<dim3(Dm / BN, T / BM, Bb), blk, 0, stream>>>(
        Pp, Vt, Ob, nullptr, T, Dm, T, T, T, Dm,
        (long)T * T, (long)Dm * T, (long)T * Dm, 1.0f, 1 | 4 | 8 | 32,
        nullptr, 0, 0, 0, invlb);

    // 6. out = O @ Wh^T + bh -> fp32
    gemm_bt<<<dim3(Dm / BN, BT / BM, 1), blk, 0, stream>>>(
        Ob, Wht, out, bh, (int)BT, Dm, Dm, Dm, Dm, Dm,
        0, 0, 0, 1.0f, 0, nullptr, 0, 0, 0, nullptr);
}

// Round 6
// 320.865 us; speedup vs baseline: 1.2641x; 1.0983x over previous
//
#include <hip/hip_runtime.h>

// B=4, T=2048, D=1024, fp32 in/out, bf16-tolerance threshold.
// prep -> fused QKV GEMM (V third written transposed) ->
// scores GEMM emitting P' = exp(s)*causal_mask (bf16; |s| <~ 2, no max-sub) ->
// rowsum (invl = 1/sum) -> PV GEMM (row-scaled epilogue) -> output proj.
// GEMM core: bf16 MFMA 16x16x32 (4x4 acc/wave — measured faster than 32x32
// here: fewer total regs incl. AGPR -> more resident waves), 128x128 tile,
// BK=64 (halves barrier-drain events vs BK=32), global_load_lds w=16.
// LDS swizzle (BK=64, 128B rows): bank group of 16B chunk c = 4c (row term
// vanishes mod 32), so slot = chunk ^ (row&7); applied on the GLOBAL column
// so the DMA's fixed lane->LDS map is preserved (permutation inside each
// 128B row segment; global coalescing per 8-lane segment intact).

typedef __attribute__((ext_vector_type(8)))  short short8;     // MFMA A/B frag
typedef __attribute__((ext_vector_type(4)))  float f4;         // MFMA 16x16 C/D
typedef __attribute__((ext_vector_type(8)))  unsigned short us8;

#define BM 128
#define BN 128
#define BK 64

__device__ inline unsigned short f2bf(float f) {
    union { float f; unsigned u; } c; c.f = f;
    unsigned u = c.u;
    return (unsigned short)((u + 0x7fffu + ((u >> 16) & 1u)) >> 16);  // RNE
}
__device__ inline float bf2f(unsigned short u) {
    union { unsigned u; float f; } c; c.u = ((unsigned)u) << 16;
    return c.f;
}
__device__ inline void gload16(const void* g, void* l) {
    __builtin_amdgcn_global_load_lds(
        (const __attribute__((address_space(1))) void*)g,
        (__attribute__((address_space(3))) void*)l,
        16, 0, 0);
}

// ---------------------------------------------------------------------------
// C = A[M,K] @ Bt[N,K]^T (+bias), bf16 in, fp32/bf16 out. 16x16x32 core.
// flags: bit0 out-bf16 | bit1 causal tile-skip | bit2 causal K-limit |
//        bit3 reverse-y | bit4 V-split transposed write (n0>=vsplit -> C2) |
//        bit5 row-scale epilogue | bit6 exp + causal-mask epilogue
// ---------------------------------------------------------------------------
__global__ __launch_bounds__(256)
void gemm_bt(const unsigned short* __restrict__ A,
             const unsigned short* __restrict__ Bt,
             void* __restrict__ C,
             const float* __restrict__ bias,
             int M, int N, int K, int lda, int ldb, int ldc,
             long sA, long sB, long sC,
             float scale, int flags,
             unsigned short* __restrict__ C2, long sC2, int Tv, int vsplit,
             const float* __restrict__ rowscale)
{
    const int b = blockIdx.z;
    A  += (long)b * sA;
    Bt += (long)b * sB;
    if (flags & 32) rowscale += (long)b * M;

    int by = blockIdx.y;
    if (flags & 8) by = gridDim.y - 1 - by;
    const int m0 = by * BM;
    const int n0 = blockIdx.x * BN;

    if ((flags & 2) && n0 > m0 + (BM - 1)) return;

    int kend = K;
    if (flags & 4) { int ke = m0 + BM; kend = ke < K ? ke : K; }
    const int numK = kend / BK;

    __shared__ unsigned short As[BM * BK];   // 16 KB
    __shared__ unsigned short Bs[BN * BK];   // 16 KB

    const int tid  = threadIdx.x;
    const int lane = tid & 63;
    const int wave = tid >> 6;
    const int wm   = wave & 1;
    const int wn   = wave >> 1;
    const int lrow = lane & 15;
    const int quad = lane >> 4;

    f4 acc[4][4];
#pragma unroll
    for (int i = 0; i < 4; ++i)
#pragma unroll
        for (int j = 0; j < 4; ++j) acc[i][j] = (f4)0.0f;

    // staging: chunk e = d*256+tid; row = e>>3; slot = e&7;
    // global chunk = slot ^ (row&7)
    const int srow = tid >> 3;             // + d*32
    const int gco  = ((tid & 7) ^ (srow & 7)) << 3;   // elems within BK
    const int rdsl = (lrow & 7);           // read-side row mixer

    for (int kt = 0; kt < numK; ++kt) {
        const int k0 = kt * BK;
#pragma unroll
        for (int d = 0; d < 4; ++d) {
            const int row = d * 32 + srow;
            const unsigned short* ga = A  + (long)(m0 + row) * lda + k0 + gco;
            const unsigned short* gb = Bt + (long)(n0 + row) * ldb + k0 + gco;
            const int ldsoff = (d * 256 + wave * 64) * 16;   // bytes, wave-uniform
            gload16(ga, (char*)As + ldsoff);
            gload16(gb, (char*)Bs + ldsoff);
        }
        __syncthreads();

#pragma unroll
        for (int ks = 0; ks < 2; ++ks) {
            const int slot = ((ks * 4 + quad) ^ rdsl) << 3;   // elem offset
            short8 af[4], bfr[4];
#pragma unroll
            for (int i = 0; i < 4; ++i) {
                af[i]  = *(const short8*)(As + (wm * 64 + i * 16 + lrow) * BK + slot);
                bfr[i] = *(const short8*)(Bs + (wn * 64 + i * 16 + lrow) * BK + slot);
            }
#pragma unroll
            for (int i = 0; i < 4; ++i)
#pragma unroll
                for (int j = 0; j < 4; ++j)
                    acc[i][j] = __builtin_amdgcn_mfma_f32_16x16x32_bf16(
                        af[i], bfr[j], acc[i][j], 0, 0, 0);
        }
        __syncthreads();
    }

    // epilogue: C/D layout col=lane&15, row=quad*4+reg (m89/m91)
    const int row0 = m0 + wm * 64 + quad * 4;
    const int col0 = n0 + wn * 64 + lrow;

    float bj[4];
#pragma unroll
    for (int j = 0; j < 4; ++j) bj[j] = bias ? bias[col0 + j * 16] : 0.0f;

    if ((flags & 16) && n0 >= vsplit) {
        // V region: write transposed to C2[b][d][t], packed 4 bf16 (8B) stores
        const int bidx  = m0 >> 11;               // T=2048 rows per batch
        const int tloc0 = (m0 & 2047) + wm * 64 + quad * 4;
#pragma unroll
        for (int j = 0; j < 4; ++j) {
            const int d = col0 + j * 16 - vsplit;
            unsigned short* base = C2 + (long)bidx * sC2 + (long)d * Tv;
#pragma unroll
            for (int i = 0; i < 4; ++i) {
                const int tt = tloc0 + i * 16;
                unsigned long long pk = 0;
#pragma unroll
                for (int r = 0; r < 4; ++r) {
                    float v = acc[i][j][r] * scale + bj[j];
                    pk |= (unsigned long long)f2bf(v) << (16 * r);
                }
                *(unsigned long long*)(base + tt) = pk;
            }
        }
        return;
    }

    const bool obf = flags & 1;
    unsigned short* Cb = (unsigned short*)C;
    float*          Cf = (float*)C;
    const long cbase = (long)b * sC;

#pragma unroll
    for (int i = 0; i < 4; ++i) {
#pragma unroll
        for (int j = 0; j < 4; ++j) {
            const int col = col0 + j * 16;
#pragma unroll
            for (int r = 0; r < 4; ++r) {
                const int row = row0 + i * 16 + r;
                float v = acc[i][j][r] * scale + bj[j];
                if (flags & 64) { v = __expf(v); if (col > row) v = 0.0f; }
                if (flags & 32) v *= rowscale[row];
                const long off = cbase + (long)row * ldc + col;
                if (obf) Cb[off] = f2bf(v);
                else     Cf[off] = v;
            }
        }
    }
}

// ---------------------------------------------------------------------------
// rowsum: invl[row] = 1 / sum(P'[row, 0..t]) ; one 256-thread block per row
// ---------------------------------------------------------------------------
__global__ void rowsum(const unsigned short* __restrict__ P,
                       float* __restrict__ invl, int T)
{
    const int t = blockIdx.x;
    const long rowoff = ((long)blockIdx.y * T + t) * T;
    const int L = t + 1;
    const int tid = threadIdx.x;
    const int lane = tid & 63, wave = tid >> 6;
    __shared__ float red[4];

    us8 raw = *(const us8*)(P + rowoff + tid * 8);
    const int i0 = tid * 8;
    float sum = 0.0f;
#pragma unroll
    for (int k = 0; k < 8; ++k)
        if (i0 + k < L) sum += bf2f(raw[k]);
    for (int o = 32; o > 0; o >>= 1) sum += __shfl_down(sum, o);
    if (lane == 0) red[wave] = sum;
    __syncthreads();
    if (tid == 0) {
        sum = red[0] + red[1] + red[2] + red[3];
        invl[(long)blockIdx.y * T + t] = 1.0f / sum;
    }
}

// ---------------------------------------------------------------------------
// prep: x cast [0,8192) + weight transposes [8192,12288) + bias concat
// ---------------------------------------------------------------------------
__global__ void prep(const float* __restrict__ x,
                     const float* __restrict__ Wq, const float* __restrict__ Wk,
                     const float* __restrict__ Wv, const float* __restrict__ Wh,
                     const float* __restrict__ bq, const float* __restrict__ bk,
                     const float* __restrict__ bv,
                     unsigned short* __restrict__ Xbf,
                     unsigned short* __restrict__ Wqkvt,
                     unsigned short* __restrict__ Wht,
                     float* __restrict__ bqkv)
{
    typedef __attribute__((ext_vector_type(4))) float f4v;
    __shared__ unsigned short tsh[32][33];
    const int bid = blockIdx.x;
    const int tid = threadIdx.x;

    if (bid < 8192) {
        const int i = bid * 256 + tid;
        f4v v = ((const f4v*)x)[i];
        unsigned long long p = (unsigned long long)f2bf(v.x)
                             | ((unsigned long long)f2bf(v.y) << 16)
                             | ((unsigned long long)f2bf(v.z) << 32)
                             | ((unsigned long long)f2bf(v.w) << 48);
        ((unsigned long long*)Xbf)[i] = p;
    } else if (bid < 12288) {
        const int wi = bid - 8192;
        const int w = wi >> 10, tile = wi & 1023;
        const float* src = (w == 0) ? Wq : (w == 1) ? Wk : (w == 2) ? Wv : Wh;
        unsigned short* dst = (w < 3) ? (Wqkvt + (size_t)w * 1024 * 1024) : Wht;
        const int c0 = (tile & 31) * 32, r0 = (tile >> 5) * 32;
        const int xx = tid & 31, yy = tid >> 5;
        for (int i = yy; i < 32; i += 8)
            tsh[i][xx] = f2bf(src[(long)(r0 + i) * 1024 + c0 + xx]);
        __syncthreads();
        for (int i = yy; i < 32; i += 8)
            dst[(long)(c0 + i) * 1024 + r0 + xx] = tsh[xx][i];
    } else {
        const int i = (bid - 12288) * 256 + tid;
        if (i < 1024) { bqkv[i] = bq[i]; bqkv[1024 + i] = bk[i]; bqkv[2048 + i] = bv[i]; }
    }
}

// ---------------------------------------------------------------------------
extern "C" void kernel_launch(void* const* d_in, const int* in_sizes, int n_in,
                              void* d_out, int out_size, void* d_ws, size_t ws_size,
                              hipStream_t stream)
{
    const float* x  = (const float*)d_in[0];
    const float* Wq = (const float*)d_in[1];
    const float* bq = (const float*)d_in[2];
    const float* Wk = (const float*)d_in[3];
    const float* bk = (const float*)d_in[4];
    const float* Wv = (const float*)d_in[5];
    const float* bv = (const float*)d_in[6];
    const float* Wh = (const float*)d_in[7];
    const float* bh = (const float*)d_in[8];
    float* out = (float*)d_out;

    const int  Bb = 4, T = 2048, Dm = 1024;
    const long BT = (long)Bb * T;

    unsigned short* ws = (unsigned short*)d_ws;
    size_t o = 0;
    unsigned short* Xbf   = ws + o; o += (size_t)BT * Dm;         // 16 MB
    unsigned short* Wqkvt = ws + o; o += (size_t)3 * Dm * Dm;     //  6 MB
    unsigned short* Wht   = ws + o; o += (size_t)Dm * Dm;         //  2 MB
    float* bqkv = (float*)(ws + o); o += (size_t)3 * Dm * 2;      // 12 KB
    unsigned short* QKV   = ws + o; o += (size_t)BT * 3 * Dm;     // 48 MB
    unsigned short* Vt    = ws + o; o += (size_t)BT * Dm;         // 16 MB
    unsigned short* Pp    = ws + o; o += (size_t)Bb * T * T;      // 32 MB (P' = exp(s))
    float* invlb = (float*)(ws + o); o += (size_t)BT * 2;         // 32 KB
    unsigned short* Ob    = ws + o;                               // 16 MB

    const dim3 blk(256);
    const long sRow3 = (long)T * 3 * Dm;

    // 1. prep
    prep<<<12292, blk, 0, stream>>>(x, Wq, Wk, Wv, Wh, bq, bk, bv,
                                    Xbf, Wqkvt, Wht, bqkv);

    // 2. fused QKV projection; V third written transposed into Vt
    gemm_bt<<<dim3(3 * Dm / BN, BT / BM, 1), blk, 0, stream>>>(
        Xbf, Wqkvt, QKV, bqkv, (int)BT, 3 * Dm, Dm, Dm, Dm, 3 * Dm,
        0, 0, 0, 1.0f, 1 | 16, Vt, (long)Dm * T, T, 2 * Dm, nullptr);

    // 3. P' = exp(Q@K^T / 32) * causal_mask -> bf16, tile-skip, rev-y
    gemm_bt<<<dim3(T / BN, T / BM, Bb), blk, 0, stream>>>(
        QKV, QKV + Dm, Pp, nullptr, T, T, Dm, 3 * Dm, 3 * Dm, T,
        sRow3, sRow3, (long)T * T, 1.0f / 32.0f, 1 | 2 | 8 | 64,
        nullptr, 0, 0, 0, nullptr);

    // 4. invl = 1/rowsum(P')
    rowsum<<<dim3(T, Bb), blk, 0, stream>>>(Pp, invlb, T);

    // 5. O = (P' @ V^T) * invl[row], plain DMA GEMM, causal K-limit, rev-y
    gemm_bt<<<dim3(Dm / BN, T / BM, Bb), blk, 0, stream>>>(
        Pp, Vt, Ob, nullptr, T, Dm, T, T, T, Dm,
        (long)T * T, (long)Dm * T, (long)T * Dm, 1.0f, 1 | 4 | 8 | 32,
        nullptr, 0, 0, 0, invlb);

    // 6. out = O @ Wh^T + bh -> fp32
    gemm_bt<<<dim3(Dm / BN, BT / BM, 1), blk, 0, stream>>>(
        Ob, Wht, out, bh, (int)BT, Dm, Dm, Dm, Dm, Dm,
        0, 0, 0, 1.0f, 0, nullptr, 0, 0, 0, nullptr);
}

// Round 7
// 318.043 us; speedup vs baseline: 1.2753x; 1.0089x over previous
//
#include <hip/hip_runtime.h>

// B=4, T=2048, D=1024, fp32 in/out, bf16-tolerance threshold.
// Algebra: out = softmax(QK^T/32)@V@Wh + bh = P_norm@(x@(Wv@Wh) + bv@Wh) + bh.
// Pipeline: prep (x cast, Wq/Wk/Wh transposes, Wv plain cast, biases) ->
//   small GEMM Wvh^T = (Wv@Wh)^T -> gemv bhh = bv@Wh + bh ->
//   fused QKV GEMM (thirds: Q,K,Vh; Vh written transposed) ->
//   scores GEMM emitting P' = exp(s)*mask (bf16; |s|<~2, no max-sub) ->
//   rowsum (invl = 1/sum) -> PV GEMM (epilogue: *invl[row] + bhh[col] -> fp32 d_out).
// GEMM core: bf16 MFMA 16x16x32, 128x128 tile, BK=64, global_load_lds w=16,
// XOR swizzle slot = chunk ^ (row&7) applied on the GLOBAL column (R6: 0 conflicts).

typedef __attribute__((ext_vector_type(8)))  short short8;     // MFMA A/B frag
typedef __attribute__((ext_vector_type(4)))  float f4;         // MFMA 16x16 C/D
typedef __attribute__((ext_vector_type(8)))  unsigned short us8;

#define BM 128
#define BN 128
#define BK 64

__device__ inline unsigned short f2bf(float f) {
    union { float f; unsigned u; } c; c.f = f;
    unsigned u = c.u;
    return (unsigned short)((u + 0x7fffu + ((u >> 16) & 1u)) >> 16);  // RNE
}
__device__ inline float bf2f(unsigned short u) {
    union { unsigned u; float f; } c; c.u = ((unsigned)u) << 16;
    return c.f;
}
__device__ inline void gload16(const void* g, void* l) {
    __builtin_amdgcn_global_load_lds(
        (const __attribute__((address_space(1))) void*)g,
        (__attribute__((address_space(3))) void*)l,
        16, 0, 0);
}

// ---------------------------------------------------------------------------
// C = A[M,K] @ Bt[N,K]^T, bf16 in, fp32/bf16 out. 16x16x32 core.
// flags: bit0 out-bf16 | bit1 causal tile-skip | bit2 causal K-limit |
//        bit3 reverse-y | bit4 V-split transposed write (n0>=vsplit -> C2) |
//        bit5 row-scale epilogue | bit6 exp + causal-mask epilogue
// Epilogue order: v = acc*scale -> [exp+mask] -> [*rowscale] -> +bias
// ---------------------------------------------------------------------------
__global__ __launch_bounds__(256)
void gemm_bt(const unsigned short* __restrict__ A,
             const unsigned short* __restrict__ Bt,
             void* __restrict__ C,
             const float* __restrict__ bias,
             int M, int N, int K, int lda, int ldb, int ldc,
             long sA, long sB, long sC,
             float scale, int flags,
             unsigned short* __restrict__ C2, long sC2, int Tv, int vsplit,
             const float* __restrict__ rowscale)
{
    const int b = blockIdx.z;
    A  += (long)b * sA;
    Bt += (long)b * sB;
    if (flags & 32) rowscale += (long)b * M;

    int by = blockIdx.y;
    if (flags & 8) by = gridDim.y - 1 - by;
    const int m0 = by * BM;
    const int n0 = blockIdx.x * BN;

    if ((flags & 2) && n0 > m0 + (BM - 1)) return;

    int kend = K;
    if (flags & 4) { int ke = m0 + BM; kend = ke < K ? ke : K; }
    const int numK = kend / BK;

    __shared__ unsigned short As[BM * BK];   // 16 KB
    __shared__ unsigned short Bs[BN * BK];   // 16 KB

    const int tid  = threadIdx.x;
    const int lane = tid & 63;
    const int wave = tid >> 6;
    const int wm   = wave & 1;
    const int wn   = wave >> 1;
    const int lrow = lane & 15;
    const int quad = lane >> 4;

    f4 acc[4][4];
#pragma unroll
    for (int i = 0; i < 4; ++i)
#pragma unroll
        for (int j = 0; j < 4; ++j) acc[i][j] = (f4)0.0f;

    // staging: chunk e = d*256+tid; row = e>>3; slot = e&7; global chunk = slot^(row&7)
    const int srow = tid >> 3;
    const int gco  = ((tid & 7) ^ (srow & 7)) << 3;
    const int rdsl = (lrow & 7);

    for (int kt = 0; kt < numK; ++kt) {
        const int k0 = kt * BK;
#pragma unroll
        for (int d = 0; d < 4; ++d) {
            const int row = d * 32 + srow;
            const unsigned short* ga = A  + (long)(m0 + row) * lda + k0 + gco;
            const unsigned short* gb = Bt + (long)(n0 + row) * ldb + k0 + gco;
            const int ldsoff = (d * 256 + wave * 64) * 16;   // bytes, wave-uniform
            gload16(ga, (char*)As + ldsoff);
            gload16(gb, (char*)Bs + ldsoff);
        }
        __syncthreads();

#pragma unroll
        for (int ks = 0; ks < 2; ++ks) {
            const int slot = ((ks * 4 + quad) ^ rdsl) << 3;
            short8 af[4], bfr[4];
#pragma unroll
            for (int i = 0; i < 4; ++i) {
                af[i]  = *(const short8*)(As + (wm * 64 + i * 16 + lrow) * BK + slot);
                bfr[i] = *(const short8*)(Bs + (wn * 64 + i * 16 + lrow) * BK + slot);
            }
#pragma unroll
            for (int i = 0; i < 4; ++i)
#pragma unroll
                for (int j = 0; j < 4; ++j)
                    acc[i][j] = __builtin_amdgcn_mfma_f32_16x16x32_bf16(
                        af[i], bfr[j], acc[i][j], 0, 0, 0);
        }
        __syncthreads();
    }

    // epilogue: C/D layout col=lane&15, row=quad*4+reg (m89/m91)
    const int row0 = m0 + wm * 64 + quad * 4;
    const int col0 = n0 + wn * 64 + lrow;

    float bj[4];
#pragma unroll
    for (int j = 0; j < 4; ++j) bj[j] = bias ? bias[col0 + j * 16] : 0.0f;

    if ((flags & 16) && n0 >= vsplit) {
        // Vh region: write transposed to C2[b][d][t], packed 4 bf16 (8B) stores
        const int bidx  = m0 >> 11;               // T=2048 rows per batch
        const int tloc0 = (m0 & 2047) + wm * 64 + quad * 4;
#pragma unroll
        for (int j = 0; j < 4; ++j) {
            const int d = col0 + j * 16 - vsplit;
            unsigned short* base = C2 + (long)bidx * sC2 + (long)d * Tv;
#pragma unroll
            for (int i = 0; i < 4; ++i) {
                const int tt = tloc0 + i * 16;
                unsigned long long pk = 0;
#pragma unroll
                for (int r = 0; r < 4; ++r) {
                    float v = acc[i][j][r] * scale + bj[j];
                    pk |= (unsigned long long)f2bf(v) << (16 * r);
                }
                *(unsigned long long*)(base + tt) = pk;
            }
        }
        return;
    }

    const bool obf = flags & 1;
    unsigned short* Cb = (unsigned short*)C;
    float*          Cf = (float*)C;
    const long cbase = (long)b * sC;

#pragma unroll
    for (int i = 0; i < 4; ++i) {
#pragma unroll
        for (int j = 0; j < 4; ++j) {
            const int col = col0 + j * 16;
#pragma unroll
            for (int r = 0; r < 4; ++r) {
                const int row = row0 + i * 16 + r;
                float v = acc[i][j][r] * scale;
                if (flags & 64) { v = __expf(v); if (col > row) v = 0.0f; }
                if (flags & 32) v *= rowscale[row];
                v += bj[j];
                const long off = cbase + (long)row * ldc + col;
                if (obf) Cb[off] = f2bf(v);
                else     Cf[off] = v;
            }
        }
    }
}

// ---------------------------------------------------------------------------
// rowsum: invl[row] = 1 / sum(P'[row, 0..t]) ; one 256-thread block per row
// ---------------------------------------------------------------------------
__global__ void rowsum(const unsigned short* __restrict__ P,
                       float* __restrict__ invl, int T)
{
    const int t = blockIdx.x;
    const long rowoff = ((long)blockIdx.y * T + t) * T;
    const int L = t + 1;
    const int tid = threadIdx.x;
    const int lane = tid & 63, wave = tid >> 6;
    __shared__ float red[4];

    us8 raw = *(const us8*)(P + rowoff + tid * 8);
    const int i0 = tid * 8;
    float sum = 0.0f;
#pragma unroll
    for (int k = 0; k < 8; ++k)
        if (i0 + k < L) sum += bf2f(raw[k]);
    for (int o = 32; o > 0; o >>= 1) sum += __shfl_down(sum, o);
    if (lane == 0) red[wave] = sum;
    __syncthreads();
    if (tid == 0) {
        sum = red[0] + red[1] + red[2] + red[3];
        invl[(long)blockIdx.y * T + t] = 1.0f / sum;
    }
}

// ---------------------------------------------------------------------------
// gemv: bhh[m] = dot(Wht[m][:], bv) + bh[m]   (coalesced bf16 row read)
// ---------------------------------------------------------------------------
__global__ void gemv_bhh(const unsigned short* __restrict__ Wht,
                         const float* __restrict__ bv,
                         const float* __restrict__ bh,
                         float* __restrict__ bhh)
{
    const int m = blockIdx.x;
    const int tid = threadIdx.x;
    const int lane = tid & 63, wave = tid >> 6;
    __shared__ float red[4];
    const unsigned short* row = Wht + (long)m * 1024;
    float s = 0.0f;
#pragma unroll
    for (int k = 0; k < 4; ++k) {
        const int idx = tid * 4 + k;
        s += bf2f(row[idx]) * bv[idx];
    }
    for (int o = 32; o > 0; o >>= 1) s += __shfl_down(s, o);
    if (lane == 0) red[wave] = s;
    __syncthreads();
    if (tid == 0) bhh[m] = red[0] + red[1] + red[2] + red[3] + bh[m];
}

// ---------------------------------------------------------------------------
// prep: x cast [0,8192) | Wv plain cast [8192,9216) |
//       transposes Wq/Wk/Wh [9216,12288) | biases [12288]
// ---------------------------------------------------------------------------
__global__ void prep(const float* __restrict__ x,
                     const float* __restrict__ Wq, const float* __restrict__ Wk,
                     const float* __restrict__ Wv, const float* __restrict__ Wh,
                     const float* __restrict__ bq, const float* __restrict__ bk,
                     unsigned short* __restrict__ Xbf,
                     unsigned short* __restrict__ Wqkvt,
                     unsigned short* __restrict__ Wht,
                     unsigned short* __restrict__ Wvb,
                     float* __restrict__ bqkv)
{
    typedef __attribute__((ext_vector_type(4))) float f4v;
    __shared__ unsigned short tsh[32][33];
    const int bid = blockIdx.x;
    const int tid = threadIdx.x;

    if (bid < 8192) {                       // cast x
        const int i = bid * 256 + tid;
        f4v v = ((const f4v*)x)[i];
        unsigned long long p = (unsigned long long)f2bf(v.x)
                             | ((unsigned long long)f2bf(v.y) << 16)
                             | ((unsigned long long)f2bf(v.z) << 32)
                             | ((unsigned long long)f2bf(v.w) << 48);
        ((unsigned long long*)Xbf)[i] = p;
    } else if (bid < 9216) {                // plain cast Wv
        const int i = (bid - 8192) * 256 + tid;
        f4v v = ((const f4v*)Wv)[i];
        unsigned long long p = (unsigned long long)f2bf(v.x)
                             | ((unsigned long long)f2bf(v.y) << 16)
                             | ((unsigned long long)f2bf(v.z) << 32)
                             | ((unsigned long long)f2bf(v.w) << 48);
        ((unsigned long long*)Wvb)[i] = p;
    } else if (bid < 12288) {               // transpose+cast Wq, Wk, Wh
        const int wi = bid - 9216;
        const int w = wi >> 10, tile = wi & 1023;
        const float* src = (w == 0) ? Wq : (w == 1) ? Wk : Wh;
        unsigned short* dst = (w == 0) ? Wqkvt : (w == 1) ? (Wqkvt + 1024 * 1024) : Wht;
        const int c0 = (tile & 31) * 32, r0 = (tile >> 5) * 32;
        const int xx = tid & 31, yy = tid >> 5;
        for (int i = yy; i < 32; i += 8)
            tsh[i][xx] = f2bf(src[(long)(r0 + i) * 1024 + c0 + xx]);
        __syncthreads();
        for (int i = yy; i < 32; i += 8)
            dst[(long)(c0 + i) * 1024 + r0 + xx] = tsh[xx][i];
    } else {                                // biases: Q, K real; Vh third = 0
        const int i = (bid - 12288) * 256 + tid;
        if (i < 1024) { bqkv[i] = bq[i]; bqkv[1024 + i] = bk[i]; bqkv[2048 + i] = 0.0f; }
    }
}

// ---------------------------------------------------------------------------
extern "C" void kernel_launch(void* const* d_in, const int* in_sizes, int n_in,
                              void* d_out, int out_size, void* d_ws, size_t ws_size,
                              hipStream_t stream)
{
    const float* x  = (const float*)d_in[0];
    const float* Wq = (const float*)d_in[1];
    const float* bq = (const float*)d_in[2];
    const float* Wk = (const float*)d_in[3];
    const float* bk = (const float*)d_in[4];
    const float* Wv = (const float*)d_in[5];
    const float* bv = (const float*)d_in[6];
    const float* Wh = (const float*)d_in[7];
    const float* bh = (const float*)d_in[8];
    float* out = (float*)d_out;

    const int  Bb = 4, T = 2048, Dm = 1024;
    const long BT = (long)Bb * T;

    unsigned short* ws = (unsigned short*)d_ws;
    size_t o = 0;
    unsigned short* Xbf   = ws + o; o += (size_t)BT * Dm;         // 16 MB
    unsigned short* Wqkvt = ws + o; o += (size_t)3 * Dm * Dm;     //  6 MB (3rd = Wvh^T)
    unsigned short* Wht   = ws + o; o += (size_t)Dm * Dm;         //  2 MB
    unsigned short* Wvb   = ws + o; o += (size_t)Dm * Dm;         //  2 MB
    float* bqkv = (float*)(ws + o); o += (size_t)3 * Dm * 2;      // 12 KB
    float* bhh  = (float*)(ws + o); o += (size_t)Dm * 2;          //  4 KB
    unsigned short* QKV   = ws + o; o += (size_t)BT * 3 * Dm;     // 48 MB
    unsigned short* Vt    = ws + o; o += (size_t)BT * Dm;         // 16 MB (Vh^T)
    unsigned short* Pp    = ws + o; o += (size_t)Bb * T * T;      // 32 MB (P' = exp(s))
    float* invlb = (float*)(ws + o); o += (size_t)BT * 2;         // 32 KB

    const dim3 blk(256);
    const long sRow3 = (long)T * 3 * Dm;

    // 1. prep: casts, transposes, biases
    prep<<<12289, blk, 0, stream>>>(x, Wq, Wk, Wv, Wh, bq, bk,
                                    Xbf, Wqkvt, Wht, Wvb, bqkv);

    // 2a. Wvh^T = (Wv@Wh)^T : C[m][n] = sum_k Wht[m][k]*Wvb[n][k] -> bf16
    gemm_bt<<<dim3(Dm / BN, Dm / BM, 1), blk, 0, stream>>>(
        Wht, Wvb, Wqkvt + 2 * Dm * Dm, nullptr, Dm, Dm, Dm, Dm, Dm, Dm,
        0, 0, 0, 1.0f, 1, nullptr, 0, 0, 0, nullptr);

    // 2b. bhh = bv@Wh + bh
    gemv_bhh<<<Dm, blk, 0, stream>>>(Wht, bv, bh, bhh);

    // 3. fused Q/K/Vh projection; Vh third written transposed into Vt
    gemm_bt<<<dim3(3 * Dm / BN, BT / BM, 1), blk, 0, stream>>>(
        Xbf, Wqkvt, QKV, bqkv, (int)BT, 3 * Dm, Dm, Dm, Dm, 3 * Dm,
        0, 0, 0, 1.0f, 1 | 16, Vt, (long)Dm * T, T, 2 * Dm, nullptr);

    // 4. P' = exp(Q@K^T / 32) * causal_mask -> bf16, tile-skip, rev-y
    gemm_bt<<<dim3(T / BN, T / BM, Bb), blk, 0, stream>>>(
        QKV, QKV + Dm, Pp, nullptr, T, T, Dm, 3 * Dm, 3 * Dm, T,
        sRow3, sRow3, (long)T * T, 1.0f / 32.0f, 1 | 2 | 8 | 64,
        nullptr, 0, 0, 0, nullptr);

    // 5. invl = 1/rowsum(P')
    rowsum<<<dim3(T, Bb), blk, 0, stream>>>(Pp, invlb, T);

    // 6. out = (P' @ Vh^T) * invl[row] + bhh[col] -> fp32 d_out
    gemm_bt<<<dim3(Dm / BN, T / BM, Bb), blk, 0, stream>>>(
        Pp, Vt, out, bhh, T, Dm, T, T, T, Dm,
        (long)T * T, (long)Dm * T, (long)T * Dm, 1.0f, 4 | 8 | 32,
        nullptr, 0, 0, 0, invlb);
}

// Round 8
// 309.241 us; speedup vs baseline: 1.3116x; 1.0285x over previous
//
#include <hip/hip_runtime.h>

// B=4, T=2048, D=1024, fp32 in/out, bf16-tolerance threshold.
// Algebra: out = softmax(QK^T/32)@V@Wh + bh = P_norm@(x@(Wv@Wh)) + (bv@Wh + bh).
// Pipeline: prep -> Wvh^T small GEMM -> gemv bhh -> fused QKV GEMM (Q,K,Vh;
//   Vh written transposed) -> scores GEMM (P' = exp(s)*mask bf16, fused
//   atomic row-sums) -> PV GEMM split-K2 (epilogue * 1/sum[row] + bhh,
//   split-1 -> fp32 partial) -> combine_upper.
// GEMM core: bf16 MFMA 16x16x32, 128x128 tile, BK=64, global_load_lds w=16,
// XOR swizzle slot = chunk ^ (row&7) on the GLOBAL column (R6: 0 conflicts).
// Flags are template params: each variant gets minimal register allocation.

typedef __attribute__((ext_vector_type(8)))  short short8;     // MFMA A/B frag
typedef __attribute__((ext_vector_type(4)))  float f4;         // MFMA 16x16 C/D
typedef __attribute__((ext_vector_type(8)))  unsigned short us8;

#define BM 128
#define BN 128
#define BK 64

// flag bits
#define F_OBF    1     // out bf16
#define F_SKIP   2     // causal tile-skip
#define F_KLIM   4     // causal K-limit
#define F_REVY   8     // reverse-y dispatch
#define F_VSPL   16    // V-split transposed write (n0>=vsplit -> C2)
#define F_RSCL   32    // epilogue * 1/rowsums[row]
#define F_EXP    64    // exp + causal-mask epilogue
#define F_RSUM   128   // atomic row-sum accumulate (with F_EXP)
#define F_SPLITK 256   // split-K2 at k=1024 (PV); split1 -> C2 fp32 partial

__device__ inline unsigned short f2bf(float f) {
    union { float f; unsigned u; } c; c.f = f;
    unsigned u = c.u;
    return (unsigned short)((u + 0x7fffu + ((u >> 16) & 1u)) >> 16);  // RNE
}
__device__ inline float bf2f(unsigned short u) {
    union { unsigned u; float f; } c; c.u = ((unsigned)u) << 16;
    return c.f;
}
__device__ inline void gload16(const void* g, void* l) {
    __builtin_amdgcn_global_load_lds(
        (const __attribute__((address_space(1))) void*)g,
        (__attribute__((address_space(3))) void*)l,
        16, 0, 0);
}

// ---------------------------------------------------------------------------
// C = A[M,K] @ Bt[N,K]^T, bf16 in, fp32/bf16 out. 16x16x32 core.
// ---------------------------------------------------------------------------
template<int FLAGS>
__global__ __launch_bounds__(256)
void gemm_bt(const unsigned short* __restrict__ A,
             const unsigned short* __restrict__ Bt,
             void* __restrict__ C,
             const float* __restrict__ bias,
             int M, int N, int K, int lda, int ldb, int ldc,
             long sA, long sB, long sC,
             float scale,
             unsigned short* __restrict__ C2, long sC2, int Tv, int vsplit,
             float* __restrict__ rowsums)
{
    const int b = blockIdx.z;
    A  += (long)b * sA;
    Bt += (long)b * sB;
    if (FLAGS & (F_RSCL | F_RSUM)) rowsums += (long)b * M;

    int by = blockIdx.y;
    if (FLAGS & F_REVY) by = gridDim.y - 1 - by;
    const int m0 = by * BM;

    int n0, split = 0;
    if (FLAGS & F_SPLITK) {
        const int nbx = N / BN;
        n0 = (blockIdx.x % nbx) * BN;
        split = blockIdx.x / nbx;
        if (split && m0 < 1024) return;
    } else {
        n0 = blockIdx.x * BN;
    }

    if ((FLAGS & F_SKIP) && n0 > m0 + (BM - 1)) return;

    int kend = K;
    if (FLAGS & F_KLIM) { int ke = m0 + BM; kend = ke < K ? ke : K; }
    int kt0 = 0;
    if (FLAGS & F_SPLITK) {
        if (split == 0) { if (kend > 1024) kend = 1024; }
        else            { kt0 = 1024 / BK; }
    }
    const int kt1 = kend / BK;

    __shared__ unsigned short As[BM * BK];   // 16 KB
    __shared__ unsigned short Bs[BN * BK];   // 16 KB

    const int tid  = threadIdx.x;
    const int lane = tid & 63;
    const int wave = tid >> 6;
    const int wm   = wave & 1;
    const int wn   = wave >> 1;
    const int lrow = lane & 15;
    const int quad = lane >> 4;

    f4 acc[4][4];
#pragma unroll
    for (int i = 0; i < 4; ++i)
#pragma unroll
        for (int j = 0; j < 4; ++j) acc[i][j] = (f4)0.0f;

    // staging: chunk e = d*256+tid; row = e>>3; slot = e&7; global chunk = slot^(row&7)
    const int srow = tid >> 3;
    const int gco  = ((tid & 7) ^ (srow & 7)) << 3;
    const int rdsl = (lrow & 7);

    for (int kt = kt0; kt < kt1; ++kt) {
        const int k0 = kt * BK;
#pragma unroll
        for (int d = 0; d < 4; ++d) {
            const int row = d * 32 + srow;
            const unsigned short* ga = A  + (long)(m0 + row) * lda + k0 + gco;
            const unsigned short* gb = Bt + (long)(n0 + row) * ldb + k0 + gco;
            const int ldsoff = (d * 256 + wave * 64) * 16;   // bytes, wave-uniform
            gload16(ga, (char*)As + ldsoff);
            gload16(gb, (char*)Bs + ldsoff);
        }
        __syncthreads();

#pragma unroll
        for (int ks = 0; ks < 2; ++ks) {
            const int slot = ((ks * 4 + quad) ^ rdsl) << 3;
            short8 af[4], bfr[4];
#pragma unroll
            for (int i = 0; i < 4; ++i) {
                af[i]  = *(const short8*)(As + (wm * 64 + i * 16 + lrow) * BK + slot);
                bfr[i] = *(const short8*)(Bs + (wn * 64 + i * 16 + lrow) * BK + slot);
            }
#pragma unroll
            for (int i = 0; i < 4; ++i)
#pragma unroll
                for (int j = 0; j < 4; ++j)
                    acc[i][j] = __builtin_amdgcn_mfma_f32_16x16x32_bf16(
                        af[i], bfr[j], acc[i][j], 0, 0, 0);
        }
        __syncthreads();
    }

    // epilogue: C/D layout col=lane&15, row=quad*4+reg (m89/m91)
    const int row0 = m0 + wm * 64 + quad * 4;
    const int col0 = n0 + wn * 64 + lrow;

    float bj[4];
#pragma unroll
    for (int j = 0; j < 4; ++j) bj[j] = bias ? bias[col0 + j * 16] : 0.0f;

    if ((FLAGS & F_VSPL) && n0 >= vsplit) {
        // Vh region: write transposed to C2[b][d][t], packed 4 bf16 (8B) stores
        const int bidx  = m0 >> 11;               // T=2048 rows per batch
        const int tloc0 = (m0 & 2047) + wm * 64 + quad * 4;
#pragma unroll
        for (int j = 0; j < 4; ++j) {
            const int d = col0 + j * 16 - vsplit;
            unsigned short* base = C2 + (long)bidx * sC2 + (long)d * Tv;
#pragma unroll
            for (int i = 0; i < 4; ++i) {
                const int tt = tloc0 + i * 16;
                unsigned long long pk = 0;
#pragma unroll
                for (int r = 0; r < 4; ++r) {
                    float v = acc[i][j][r] * scale + bj[j];
                    pk |= (unsigned long long)f2bf(v) << (16 * r);
                }
                *(unsigned long long*)(base + tt) = pk;
            }
        }
        return;
    }

    float inv[16];
    if (FLAGS & F_RSCL) {
#pragma unroll
        for (int i = 0; i < 4; ++i)
#pragma unroll
            for (int r = 0; r < 4; ++r)
                inv[i * 4 + r] = 1.0f / rowsums[row0 + i * 16 + r];
    }

    float rs[16];
    if (FLAGS & F_RSUM) {
#pragma unroll
        for (int k = 0; k < 16; ++k) rs[k] = 0.0f;
    }

    unsigned short* Cb = (unsigned short*)C;
    float*          Cf = ((FLAGS & F_SPLITK) && split) ? (float*)C2 : (float*)C;
    const long cbase = (long)b * sC;

#pragma unroll
    for (int i = 0; i < 4; ++i) {
#pragma unroll
        for (int j = 0; j < 4; ++j) {
            const int col = col0 + j * 16;
#pragma unroll
            for (int r = 0; r < 4; ++r) {
                const int row = row0 + i * 16 + r;
                float v = acc[i][j][r] * scale;
                if (FLAGS & F_EXP) { v = __expf(v); if (col > row) v = 0.0f; }
                if (FLAGS & F_RSUM) rs[i * 4 + r] += v;
                if (FLAGS & F_RSCL) v *= inv[i * 4 + r];
                if (!((FLAGS & F_SPLITK) && split)) v += bj[j];
                const long off = cbase + (long)row * ldc + col;
                if (FLAGS & F_OBF) Cb[off] = f2bf(v);
                else               Cf[off] = v;
            }
        }
    }

    if (FLAGS & F_RSUM) {
        // reduce across the 16 col-lanes (lrow bits), then one atomic per row
#pragma unroll
        for (int k = 0; k < 16; ++k) {
            rs[k] += __shfl_xor(rs[k], 1);
            rs[k] += __shfl_xor(rs[k], 2);
            rs[k] += __shfl_xor(rs[k], 4);
            rs[k] += __shfl_xor(rs[k], 8);
        }
        if (lrow == 0) {
#pragma unroll
            for (int i = 0; i < 4; ++i)
#pragma unroll
                for (int r = 0; r < 4; ++r)
                    atomicAdd(&rowsums[row0 + i * 16 + r], rs[i * 4 + r]);
        }
    }
}

// ---------------------------------------------------------------------------
// combine_upper: out[b][1024+..][*] += part[b][1024+..][*]  (float4)
// ---------------------------------------------------------------------------
__global__ void combine_upper(float* __restrict__ out,
                              const float* __restrict__ part)
{
    const long base = ((long)blockIdx.y * 2048 + 1024) * 1024 / 4;  // f4 units
    const long i = base + blockIdx.x * 256 + threadIdx.x;
    f4 a = ((f4*)out)[i];
    f4 bb = ((const f4*)part)[i];
    a.x += bb.x; a.y += bb.y; a.z += bb.z; a.w += bb.w;
    ((f4*)out)[i] = a;
}

// ---------------------------------------------------------------------------
// gemv: bhh[m] = dot(Wht[m][:], bv) + bh[m]
// ---------------------------------------------------------------------------
__global__ void gemv_bhh(const unsigned short* __restrict__ Wht,
                         const float* __restrict__ bv,
                         const float* __restrict__ bh,
                         float* __restrict__ bhh)
{
    const int m = blockIdx.x;
    const int tid = threadIdx.x;
    const int lane = tid & 63, wave = tid >> 6;
    __shared__ float red[4];
    const unsigned short* row = Wht + (long)m * 1024;
    float s = 0.0f;
#pragma unroll
    for (int k = 0; k < 4; ++k) {
        const int idx = tid * 4 + k;
        s += bf2f(row[idx]) * bv[idx];
    }
    for (int o = 32; o > 0; o >>= 1) s += __shfl_down(s, o);
    if (lane == 0) red[wave] = s;
    __syncthreads();
    if (tid == 0) bhh[m] = red[0] + red[1] + red[2] + red[3] + bh[m];
}

// ---------------------------------------------------------------------------
// prep: x cast [0,8192) | Wv plain cast [8192,9216) |
//       transposes Wq/Wk/Wh [9216,12288) | biases [12288]
// ---------------------------------------------------------------------------
__global__ void prep(const float* __restrict__ x,
                     const float* __restrict__ Wq, const float* __restrict__ Wk,
                     const float* __restrict__ Wv, const float* __restrict__ Wh,
                     const float* __restrict__ bq, const float* __restrict__ bk,
                     unsigned short* __restrict__ Xbf,
                     unsigned short* __restrict__ Wqkvt,
                     unsigned short* __restrict__ Wht,
                     unsigned short* __restrict__ Wvb,
                     float* __restrict__ bqkv)
{
    __shared__ unsigned short tsh[32][33];
    const int bid = blockIdx.x;
    const int tid = threadIdx.x;

    if (bid < 8192) {                       // cast x
        const int i = bid * 256 + tid;
        f4 v = ((const f4*)x)[i];
        unsigned long long p = (unsigned long long)f2bf(v.x)
                             | ((unsigned long long)f2bf(v.y) << 16)
                             | ((unsigned long long)f2bf(v.z) << 32)
                             | ((unsigned long long)f2bf(v.w) << 48);
        ((unsigned long long*)Xbf)[i] = p;
    } else if (bid < 9216) {                // plain cast Wv
        const int i = (bid - 8192) * 256 + tid;
        f4 v = ((const f4*)Wv)[i];
        unsigned long long p = (unsigned long long)f2bf(v.x)
                             | ((unsigned long long)f2bf(v.y) << 16)
                             | ((unsigned long long)f2bf(v.z) << 32)
                             | ((unsigned long long)f2bf(v.w) << 48);
        ((unsigned long long*)Wvb)[i] = p;
    } else if (bid < 12288) {               // transpose+cast Wq, Wk, Wh
        const int wi = bid - 9216;
        const int w = wi >> 10, tile = wi & 1023;
        const float* src = (w == 0) ? Wq : (w == 1) ? Wk : Wh;
        unsigned short* dst = (w == 0) ? Wqkvt : (w == 1) ? (Wqkvt + 1024 * 1024) : Wht;
        const int c0 = (tile & 31) * 32, r0 = (tile >> 5) * 32;
        const int xx = tid & 31, yy = tid >> 5;
        for (int i = yy; i < 32; i += 8)
            tsh[i][xx] = f2bf(src[(long)(r0 + i) * 1024 + c0 + xx]);
        __syncthreads();
        for (int i = yy; i < 32; i += 8)
            dst[(long)(c0 + i) * 1024 + r0 + xx] = tsh[xx][i];
    } else {                                // biases: Q, K real; Vh third = 0
        const int i = (bid - 12288) * 256 + tid;
        if (i < 1024) { bqkv[i] = bq[i]; bqkv[1024 + i] = bk[i]; bqkv[2048 + i] = 0.0f; }
    }
}

// ---------------------------------------------------------------------------
extern "C" void kernel_launch(void* const* d_in, const int* in_sizes, int n_in,
                              void* d_out, int out_size, void* d_ws, size_t ws_size,
                              hipStream_t stream)
{
    const float* x  = (const float*)d_in[0];
    const float* Wq = (const float*)d_in[1];
    const float* bq = (const float*)d_in[2];
    const float* Wk = (const float*)d_in[3];
    const float* bk = (const float*)d_in[4];
    const float* Wv = (const float*)d_in[5];
    const float* bv = (const float*)d_in[6];
    const float* Wh = (const float*)d_in[7];
    const float* bh = (const float*)d_in[8];
    float* out = (float*)d_out;

    const int  Bb = 4, T = 2048, Dm = 1024;
    const long BT = (long)Bb * T;

    unsigned short* ws = (unsigned short*)d_ws;
    size_t o = 0;
    unsigned short* Xbf   = ws + o; o += (size_t)BT * Dm;         // 16 MB
    unsigned short* Wqkvt = ws + o; o += (size_t)3 * Dm * Dm;     //  6 MB (3rd = Wvh^T)
    unsigned short* Wht   = ws + o; o += (size_t)Dm * Dm;         //  2 MB
    unsigned short* Wvb   = ws + o; o += (size_t)Dm * Dm;         //  2 MB
    float* bqkv = (float*)(ws + o); o += (size_t)3 * Dm * 2;      // 12 KB
    float* bhh  = (float*)(ws + o); o += (size_t)Dm * 2;          //  4 KB
    float* sums = (float*)(ws + o); o += (size_t)BT * 2;          // 32 KB
    unsigned short* QKV   = ws + o; o += (size_t)BT * 3 * Dm;     // 48 MB
    unsigned short* Vt    = ws + o; o += (size_t)BT * Dm;         // 16 MB (Vh^T)
    unsigned short* Pp    = ws + o; o += (size_t)Bb * T * T;      // 32 MB (P' = exp(s))
    float* part = (float*)(ws + o);                               // 32 MB fp32 partial

    const dim3 blk(256);
    const long sRow3 = (long)T * 3 * Dm;

    // 0. zero row-sum accumulators (32 KB)
    hipMemsetAsync(sums, 0, (size_t)BT * sizeof(float), stream);

    // 1. prep: casts, transposes, biases
    prep<<<12289, blk, 0, stream>>>(x, Wq, Wk, Wv, Wh, bq, bk,
                                    Xbf, Wqkvt, Wht, Wvb, bqkv);

    // 2a. Wvh^T = (Wv@Wh)^T : C[m][n] = sum_k Wht[m][k]*Wvb[n][k] -> bf16
    gemm_bt<F_OBF><<<dim3(Dm / BN, Dm / BM, 1), blk, 0, stream>>>(
        Wht, Wvb, Wqkvt + 2 * Dm * Dm, nullptr, Dm, Dm, Dm, Dm, Dm, Dm,
        0, 0, 0, 1.0f, nullptr, 0, 0, 0, nullptr);

    // 2b. bhh = bv@Wh + bh
    gemv_bhh<<<Dm, blk, 0, stream>>>(Wht, bv, bh, bhh);

    // 3. fused Q/K/Vh projection; Vh third written transposed into Vt
    gemm_bt<F_OBF | F_VSPL><<<dim3(3 * Dm / BN, BT / BM, 1), blk, 0, stream>>>(
        Xbf, Wqkvt, QKV, bqkv, (int)BT, 3 * Dm, Dm, Dm, Dm, 3 * Dm,
        0, 0, 0, 1.0f, Vt, (long)Dm * T, T, 2 * Dm, nullptr);

    // 4. P' = exp(Q@K^T / 32) * mask -> bf16 + atomic row-sums, tile-skip, rev-y
    gemm_bt<F_OBF | F_SKIP | F_REVY | F_EXP | F_RSUM>
        <<<dim3(T / BN, T / BM, Bb), blk, 0, stream>>>(
        QKV, QKV + Dm, Pp, nullptr, T, T, Dm, 3 * Dm, 3 * Dm, T,
        sRow3, sRow3, (long)T * T, 1.0f / 32.0f,
        nullptr, 0, 0, 0, sums);

    // 5. out = (P' @ Vh^T) * (1/sums[row]) + bhh, split-K2 (split1 -> part)
    gemm_bt<F_KLIM | F_REVY | F_RSCL | F_SPLITK>
        <<<dim3(2 * Dm / BN, T / BM, Bb), blk, 0, stream>>>(
        Pp, Vt, out, bhh, T, Dm, T, T, T, Dm,
        (long)T * T, (long)Dm * T, (long)T * Dm, 1.0f,
        (unsigned short*)part, 0, 0, 0, sums);

    // 6. out upper rows += part upper rows
    combine_upper<<<dim3(1024, Bb), blk, 0, stream>>>(out, part);
}